// Round 18
// baseline (832.637 us; speedup 1.0000x reference)
//
#include <hip/hip_runtime.h>
#include <math.h>

// ---------------------------------------------------------------------------
// SwinV2-style block (DIM=192, HEADS=6, WS=8, SHIFT=4) on MI355X.
// Round 18: superkernel merges — setup(ln1+prep+rpb+zero), stage2(conv1||qkv),
// stage3(conv2||attn). Bodies byte-equivalent to r17 (device fns + LDS
// union). Removes 5 launch tails and lets independent latency-bound kernels
// co-schedule. proj/mlp/se unchanged from r17 (best: 636us).
// ---------------------------------------------------------------------------

typedef unsigned short u16;
typedef __attribute__((ext_vector_type(8))) short short8;
typedef __attribute__((ext_vector_type(4))) float f32x4;

#define DI static __device__ __forceinline__

DI float b2f(u16 u){ union{unsigned u; float f;} v; v.u = ((unsigned)u)<<16; return v.f; }
DI u16 f2b(float f){ union{float f; unsigned u;} v; v.f = f; unsigned r = v.u + 0x7fffu + ((v.u>>16)&1u); return (u16)(r>>16); }
// tanh-GELU with hardware rcp (no VCC-serialized division).
DI float gelu_f(float x){
  const float u = x*(0.7978845608f + 0.0356774081f*x*x);
  const float r = __builtin_amdgcn_rcpf(1.0f + __expf(2.0f*u));
  return x - x*r;
}

#define C2PLANE (12582912L)   // 131072*96

// ===================== device bodies =======================================

// ---- LayerNorm row-group (4 rows/block) ----
DI void ln_body(int bid, int tid, const float* __restrict__ in,
                const float* __restrict__ w, const float* __restrict__ b,
                u16* __restrict__ out)
{
  const int row  = bid*4 + (tid>>6);
  const int lane = tid & 63;
  const float* r = in + (long)row*192;
  float v0 = r[lane], v1 = r[lane+64], v2 = r[lane+128];
  float s = v0+v1+v2;
  #pragma unroll
  for (int m=1;m<64;m<<=1) s += __shfl_xor(s, m);
  float mu = s*(1.0f/192.0f);
  float d0=v0-mu, d1=v1-mu, d2=v2-mu;
  float q = d0*d0+d1*d1+d2*d2;
  #pragma unroll
  for (int m=1;m<64;m<<=1) q += __shfl_xor(q, m);
  float rstd = rsqrtf(q*(1.0f/192.0f)+1e-5f);
  u16* o = out + (long)row*192;
  o[lane]     = f2b(d0*rstd*w[lane]    +b[lane]);
  o[lane+64]  = f2b(d1*rstd*w[lane+64] +b[lane+64]);
  o[lane+128] = f2b(d2*rstd*w[lane+128]+b[lane+128]);
}

// ---- weight prep (one 256-elem slice per block) ----
DI void prep_body(int bid, int tid,
    const float* __restrict__ qkv_w, const float* __restrict__ q_bias,
    const float* __restrict__ v_bias, const float* __restrict__ proj_w,
    const float* __restrict__ fc1_w, const float* __restrict__ fc2_w,
    const float* __restrict__ cab1_w, const float* __restrict__ cab2_w,
    const float* __restrict__ lgs,
    float* __restrict__ qkvbias, u16* __restrict__ wqkv, u16* __restrict__ wproj,
    u16* __restrict__ wfc1, u16* __restrict__ wfc2, u16* __restrict__ wt1,
    u16* __restrict__ wt2, float* __restrict__ scale6)
{
  int o = bid*256 + tid;
  if (o < 576){ qkvbias[o] = (o<192)? q_bias[o] : ((o<384)? 0.f : v_bias[o-384]); return; }
  o -= 576;
  if (o < 110592){ wqkv[o] = f2b(qkv_w[o]); return; } o -= 110592;
  if (o < 36864){ // wproj packed: [nr(12)][ks(6)][lane(64)][e(8)]
    const int e = o&7, lane = (o>>3)&63, ks = (o>>9)%6, nr = o/3072;
    const int row = nr*16 + (lane&15), col = ks*32 + (lane>>4)*8 + e;
    wproj[o] = f2b(proj_w[row*192 + col]); return; } o -= 36864;
  if (o < 147456){ // wfc1 packed: [p(12)][nr(4)][ks(6)][lane][e]
    const int e = o&7, lane = (o>>3)&63, ks = (o>>9)%6, rest = o/3072;
    const int nr = rest&3, p = rest>>2;
    const int row = p*64 + nr*16 + (lane&15), col = ks*32 + (lane>>4)*8 + e;
    wfc1[o] = f2b(fc1_w[row*192 + col]); return; } o -= 147456;
  if (o < 147456){ // wfc2 packed: [p(12)][nr2(12)][ks2(2)][lane][e]
    const int e = o&7, lane = (o>>3)&63, ks2 = (o>>9)&1, rest = o>>10;
    const int nr2 = rest%12, p = rest/12;
    const int row = nr2*16 + (lane&15);
    const int col = p*64 + ks2*32 + (lane>>4)*8 + e;
    wfc2[o] = f2b(fc2_w[row*768 + col]); return; } o -= 147456;
  if (o < 110592){ // wt1[s][oc(64)][ic(192)]
    int s = o/12288, r = o%12288, oc = r/192, ic = r%192, kh = s/3, kw = s%3;
    wt1[o] = f2b(cab1_w[((oc*192+ic)*3+kh)*3+kw]); return; } o -= 110592;
  if (o < 110592){ // wt2[s][oc(192)][ic(64)]
    int s = o/12288, r = o%12288, oc = r/64, ic = r%64, kh = s/3, kw = s%3;
    wt2[o] = f2b(cab2_w[((oc*64+ic)*3+kh)*3+kw]); return; } o -= 110592;
  if (o < 6){ scale6[o] = expf(fminf(lgs[o], logf(100.f))); }
}

// ---- CPB MLP + ssum zeroing (single block) ----
DI void rpb_body(int tid, float* hb,
    const float* __restrict__ w1, const float* __restrict__ b1,
    const float* __restrict__ w2, float* __restrict__ rpbL,
    float* __restrict__ ssum)
{
  for (int i=tid; i<1536; i+=256) ssum[i] = 0.f;
  if (tid < 225){
    int di = tid/15, dj = tid%15;
    float vi = (di-7)*(8.0f/7.0f), vj = (dj-7)*(8.0f/7.0f);
    float t0 = (vi==0.f)?0.f:copysignf(log2f(fabsf(vi)+1.f)*(1.f/3.f), vi);
    float t1 = (vj==0.f)?0.f:copysignf(log2f(fabsf(vj)+1.f)*(1.f/3.f), vj);
    float acc[6] = {0,0,0,0,0,0};
    for (int hd=0; hd<512; ++hd){
      float a = fmaxf(t0*w1[hd*2] + t1*w1[hd*2+1] + b1[hd], 0.f);
      #pragma unroll
      for (int h=0;h<6;++h) acc[h] += a*w2[h*512+hd];
    }
    #pragma unroll
    for (int h=0;h<6;++h) hb[tid*6+h] = acc[h];
  }
  __syncthreads();
  for (int o = tid; o < 24576; o += 256){
    int i = o&3, lane = (o>>2)&63, mK = (o>>8)&3, nQ = (o>>10)&3, h = o>>12;
    int q = nQ*16 + (lane&15), k = mK*16 + (lane>>4)*4 + i;
    int idx = ((q>>3)-(k>>3)+7)*15 + ((q&7)-(k&7)+7);
    rpbL[o] = 16.0f/(1.0f+expf(-hb[idx*6+h]));
  }
}

// ---- gemm4 body (qkv): out = A @ W^T, LDS = As(51200B)+Bs(25600B) ----
template<int KK, int NN>
DI void gemm4_body(char* LDSU, int bid, int tid,
    const u16* __restrict__ A, const u16* __restrict__ W,
    const float* __restrict__ bias, u16* __restrict__ outb)
{
  constexpr int NP = NN/64;
  u16* As = (u16*)LDSU;
  u16* Bs = (u16*)(LDSU + 102400);
  const int w = tid>>6, lane = tid&63;
  const int fr = lane&15, g = lane>>4;
  const int m0 = bid*128;
  u16* obuf = Bs;

  #pragma unroll
  for (int i=0;i<12;++i){ const int id=tid+i*256, row=id/24, cc=id%24;
    *(short8*)&As[row*200+cc*8] =
      *(const short8*)(A + (long)(m0+row)*KK + cc*8); }

  short8 breg[6];
  #define LOADB(p) { \
    _Pragma("unroll") \
    for (int i=0;i<6;++i){ const int id=tid+i*256, br=id/24, cc=id%24; \
      breg[i] = *(const short8*)(W + (long)((p)*64+br)*KK + cc*8); } }
  #define STOREB() { \
    _Pragma("unroll") \
    for (int i=0;i<6;++i){ const int id=tid+i*256, br=id/24, cc=id%24; \
      *(short8*)&Bs[br*200+cc*8] = breg[i]; } }

  LOADB(0);
  for (int p=0; p<NP; ++p){
    __syncthreads();
    STOREB();
    __syncthreads();
    if (p+1 < NP) LOADB(p+1);
    f32x4 acc[2][4];
    #pragma unroll
    for (int a=0;a<2;++a)
      #pragma unroll
      for (int b=0;b<4;++b) acc[a][b] = (f32x4){0.f,0.f,0.f,0.f};
    #pragma unroll
    for (int ks=0; ks<6; ++ks){
      short8 af0 = *(const short8*)&As[(w*32+   fr)*200 + ks*32 + g*8];
      short8 af1 = *(const short8*)&As[(w*32+16+fr)*200 + ks*32 + g*8];
      #pragma unroll
      for (int nr=0;nr<4;++nr){
        short8 bf = *(const short8*)&Bs[(nr*16+fr)*200 + ks*32 + g*8];
        acc[0][nr] = __builtin_amdgcn_mfma_f32_16x16x32_bf16(af0, bf, acc[0][nr], 0,0,0);
        acc[1][nr] = __builtin_amdgcn_mfma_f32_16x16x32_bf16(af1, bf, acc[1][nr], 0,0,0);
      } }
    __syncthreads();
    #pragma unroll
    for (int mr=0;mr<2;++mr)
      #pragma unroll
      for (int nr=0;nr<4;++nr){
        const float bc = bias[p*64+nr*16+fr];
        #pragma unroll
        for (int i=0;i<4;++i){
          const int tok = w*32+mr*16+g*4+i;
          obuf[tok*72 + nr*16+fr] = f2b(acc[mr][nr][i] + bc); } }
    __syncthreads();
    #pragma unroll
    for (int j=0;j<4;++j){
      const int idx = tid + j*256, tok = idx>>3, cc = idx&7;
      *(short8*)(outb + (long)(m0+tok)*NN + p*64 + cc*8) =
          *(const short8*)&obuf[tok*72 + cc*8]; }
  }
  #undef LOADB
  #undef STOREB
}

// ---- conv3x3 implicit GEMM body; LDS = Ah(37440B)+Wl ----
template<int EPI, int CG, int IC, int OCT, int OCP, int NR, int TG>
DI void conv4_body(char* LDSU, int bx, int by, int tid,
    const u16* __restrict__ A, const u16* __restrict__ Wt,
    const float* __restrict__ bias, u16* __restrict__ outb,
    float* __restrict__ ssum)
{
  constexpr int NTG = 9/TG, S = CG*NTG;
  constexpr int WN = (TG*OCP*4 + 255)/256;
  u16* Ah = (u16*)LDSU;
  u16* Wl = (u16*)(LDSU + 37440);
  const int w = tid>>6, lane = tid&63;
  const int fr = lane&15, g = lane>>4;
  const int b = bx>>6, y0 = (bx&63)*2;
  const int oc0 = by*OCP;
  const int wrow = w>>1, wcol = (w&1)*64;

  f32x4 acc[4][NR];
  #pragma unroll
  for (int a=0;a<4;++a)
    #pragma unroll
    for (int n=0;n<NR;++n) acc[a][n] = (f32x4){0.f,0.f,0.f,0.f};

  short8 hreg[8], wreg[WN];

  #define PRELOAD(s) { \
    const int cg_=(s)/NTG, tg_=(s)%NTG; \
    if (tg_==0){ \
      _Pragma("unroll") \
      for (int i=0;i<8;++i){ \
        const int id=tid+i*256, p=id>>9, x=(id>>2)&127, cc=id&3, y=y0+p-1; \
        short8 v={0,0,0,0,0,0,0,0}; \
        if ((unsigned)y<128u) \
          v = *(const short8*)(A + (long)((((b<<7)|y)<<7)|x)*IC + cg_*32 + cc*8); \
        hreg[i]=v; } } \
    _Pragma("unroll") \
    for (int i=0;i<WN;++i){ \
      const int id=tid+i*256; \
      if (id < TG*OCP*4){ \
        const int t=id/(OCP*4), r=id%(OCP*4), oc=r>>2, cc=r&3; \
        wreg[i] = *(const short8*)(Wt + \
            (long)((tg_*TG+t)*OCT + oc0 + oc)*IC + cg_*32 + cc*8); } } }

  #define STORE_STAGED(s) { \
    const int tg_=(s)%NTG; \
    if (tg_==0){ \
      _Pragma("unroll") \
      for (int i=0;i<8;++i){ \
        const int id=tid+i*256, p=id>>9, x=(id>>2)&127, cc=id&3; \
        *(short8*)&Ah[(p*130 + x + 1)*36 + cc*8] = hreg[i]; } \
      if (tid < 32){ \
        const int p=tid>>3, r=tid&7, col=(r>>2)?129:0, cc=r&3; \
        *(short8*)&Ah[(p*130 + col)*36 + cc*8] = (short8){0,0,0,0,0,0,0,0}; } } \
    _Pragma("unroll") \
    for (int i=0;i<WN;++i){ \
      const int id=tid+i*256; \
      if (id < TG*OCP*4){ \
        const int t=id/(OCP*4), r=id%(OCP*4), oc=r>>2, cc=r&3; \
        *(short8*)&Wl[(t*OCP+oc)*36 + cc*8] = wreg[i]; } } }

  #define COMPUTE(s) { \
    const int tg_=(s)%NTG; \
    _Pragma("unroll") \
    for (int t=0;t<TG;++t){ \
      const int tap=tg_*TG+t, dy=tap/3, dx=tap%3; \
      short8 bf[NR]; \
      _Pragma("unroll") \
      for (int nr=0;nr<NR;++nr) \
        bf[nr] = *(const short8*)&Wl[(t*OCP + nr*16 + fr)*36 + g*8]; \
      short8 af2[4]; \
      _Pragma("unroll") \
      for (int mr=0;mr<4;++mr) \
        af2[mr] = *(const short8*)&Ah[((wrow+dy)*130 + wcol + mr*16 + fr + dx)*36 + g*8]; \
      _Pragma("unroll") \
      for (int mr=0;mr<4;++mr) \
        _Pragma("unroll") \
        for (int nr=0;nr<NR;++nr) \
          acc[mr][nr] = __builtin_amdgcn_mfma_f32_16x16x32_bf16(af2[mr], bf[nr], acc[mr][nr], 0,0,0); } }

  PRELOAD(0);
  for (int s=0; s<S; ++s){
    __syncthreads();
    STORE_STAGED(s);
    __syncthreads();
    if (s+1 < S) PRELOAD(s+1);
    COMPUTE(s);
  }
  #undef PRELOAD
  #undef STORE_STAGED
  #undef COMPUTE

  if constexpr (EPI==2){
    #pragma unroll
    for (int nr=0;nr<NR;++nr){
      const float bc = bias[oc0 + nr*16 + fr];
      float s = 0.f;
      #pragma unroll
      for (int mr=0;mr<4;++mr)
        #pragma unroll
        for (int i=0;i<4;++i) s += acc[mr][nr][i] + bc;
      s += __shfl_xor(s,16); s += __shfl_xor(s,32);
      if (lane < 16) atomicAdd(&ssum[b*192 + oc0 + nr*16 + lane], s);
    }
  }

  u16* ob = Ah;
  const long tb = (long)(((b<<7)|y0)<<7);
  __syncthreads();
  if constexpr (EPI==1){
    #pragma unroll
    for (int mr=0;mr<4;++mr)
      #pragma unroll
      for (int nr=0;nr<NR;++nr){
        const float bc = bias[nr*16 + fr];
        #pragma unroll
        for (int i=0;i<4;++i){
          const int tok = wrow*128 + wcol + mr*16 + g*4 + i;
          ob[tok*72 + nr*16+fr] = f2b(gelu_f(acc[mr][nr][i] + bc));
        }
      }
    __syncthreads();
    #pragma unroll
    for (int j=0;j<8;++j){
      const int idx = tid + j*256, tok = idx>>3, cc = idx&7;
      *(short8*)(outb + (tb+tok)*OCP + cc*8) = *(const short8*)&ob[tok*72 + cc*8];
    }
  } else {
    const long pbase = (long)by*C2PLANE;
    #pragma unroll
    for (int h=0;h<2;++h){
      if (h) __syncthreads();
      if (wrow == h){
        #pragma unroll
        for (int mr=0;mr<4;++mr)
          #pragma unroll
          for (int nr=0;nr<NR;++nr){
            const float bc = bias[oc0 + nr*16 + fr];
            #pragma unroll
            for (int i=0;i<4;++i){
              const int tok = wcol + mr*16 + g*4 + i;
              ob[tok*104 + nr*16+fr] = f2b(acc[mr][nr][i] + bc);
            }
          }
      }
      __syncthreads();
      #pragma unroll
      for (int j=0;j<6;++j){
        const int idx = tid + j*256, t = idx/12, cc = idx%12;
        *(short8*)(outb + pbase + (tb + h*128 + t)*96 + cc*8) =
            *(const short8*)&ob[t*104 + cc*8];
      }
    }
  }
}

// ---- attention body; LDS = lidx(1024B)+region(256B)+p_s(36864B) ----
DI void attn_body(char* LDSU, int bid, int tid,
    const u16* __restrict__ qkv, const float* __restrict__ rpbL,
    const float* __restrict__ scale6, u16* __restrict__ aout)
{
  int*  lidx_s   = (int*)LDSU;                 // [4][64]
  char* region_s = LDSU + 1024;                // [4][64]
  u16*  p_sb     = (u16*)(LDSU + 1280);        // [4][64*72]
  const int w = tid>>6, lane = tid&63;
  const int task = bid*4 + w;
  const int win = task/6, h = task - win*6;
  const int b = win>>8, wn = win&255, wy = wn>>4, wx = wn&15;
  {
    int i = lane>>3, j = lane&7;
    int hs = wy*8+i, ws = wx*8+j;
    lidx_s[w*64+lane] = (b<<14) | (((hs+4)&127)<<7) | ((ws+4)&127);
    int hb = hs<120?0:(hs<124?1:2), wb = ws<120?0:(ws<124?1:2);
    region_s[w*64+lane] = (char)(hb*3+wb);
  }
  __syncthreads();
  const int g = lane>>4, l15 = lane&15;
  const int* lidx = lidx_s + w*64;
  const char* region = region_s + w*64;
  u16* p_s = p_sb + w*4608;
  const bool edge = (wy==15) || (wx==15);
  const float scl = scale6[h];
  const f32x4 zf = {0.f,0.f,0.f,0.f};

  short8 kf[4];
  #pragma unroll
  for (int mt=0; mt<4; ++mt){
    const long base = (long)lidx[mt*16+l15]*576 + 192 + h*32 + g*8;
    short8 r = *(const short8*)(qkv + base);
    float f[8]; float ss = 0.f;
    #pragma unroll
    for (int e=0;e<8;++e){ f[e] = b2f((u16)r[e]); ss += f[e]*f[e]; }
    ss += __shfl_xor(ss,16); ss += __shfl_xor(ss,32);
    const float inv = 1.0f/fmaxf(sqrtf(ss), 1e-12f);
    #pragma unroll
    for (int e=0;e<8;++e) kf[mt][e] = (short)f2b(f[e]*inv);
  }

  #pragma unroll
  for (int nt=0; nt<4; ++nt){
    short8 qf;
    {
      const long base = (long)lidx[nt*16+l15]*576 + h*32 + g*8;
      short8 r = *(const short8*)(qkv + base);
      float f[8]; float ss = 0.f;
      #pragma unroll
      for (int e=0;e<8;++e){ f[e] = b2f((u16)r[e]); ss += f[e]*f[e]; }
      ss += __shfl_xor(ss,16); ss += __shfl_xor(ss,32);
      const float inv = 1.0f/fmaxf(sqrtf(ss), 1e-12f);
      #pragma unroll
      for (int e=0;e<8;++e) qf[e] = (short)f2b(f[e]*inv);
    }
    f32x4 st[4];
    #pragma unroll
    for (int mt=0; mt<4; ++mt)
      st[mt] = __builtin_amdgcn_mfma_f32_16x16x32_bf16(kf[mt], qf, zf, 0, 0, 0);
    float lv[16];
    const float* rp = rpbL + ((h*4+nt)*4)*256 + lane*4;
    const int rq = edge ? region[nt*16+l15] : 0;
    #pragma unroll
    for (int mt=0; mt<4; ++mt){
      const f32x4 rb = *(const f32x4*)(rp + mt*256);
      #pragma unroll
      for (int i=0;i<4;++i){
        float v = st[mt][i]*scl + rb[i];
        if (edge && region[mt*16+g*4+i] != rq) v -= 100.0f;
        lv[mt*4+i] = v;
      }
    }
    float mx = lv[0];
    #pragma unroll
    for (int t=1;t<16;++t) mx = fmaxf(mx, lv[t]);
    mx = fmaxf(mx, __shfl_xor(mx,16)); mx = fmaxf(mx, __shfl_xor(mx,32));
    float sum = 0.f;
    #pragma unroll
    for (int t=0;t<16;++t){ lv[t] = __expf(lv[t]-mx); sum += lv[t]; }
    sum += __shfl_xor(sum,16); sum += __shfl_xor(sum,32);
    const float isum = 1.0f/sum;
    u16* pr = p_s + (nt*16+l15)*72;
    #pragma unroll
    for (int mt=0; mt<4; ++mt){
      #pragma unroll
      for (int j=0;j<2;++j){
        unsigned lo = f2b(lv[mt*4+2*j]  *isum);
        unsigned hi = f2b(lv[mt*4+2*j+1]*isum);
        *(unsigned*)(pr + mt*16 + g*4 + 2*j) = lo | (hi<<16);
      }
    }
  }

  short8 vf[2][2];
  #pragma unroll
  for (int nd=0; nd<2; ++nd)
    #pragma unroll
    for (int kc=0; kc<2; ++kc)
      #pragma unroll
      for (int e=0;e<8;++e){
        const int tok = kc*32 + g*8 + e;
        vf[nd][kc][e] = (short)qkv[(long)lidx[tok]*576 + 384 + h*32 + nd*16 + l15];
      }

  __syncthreads();

  #pragma unroll
  for (int mt=0; mt<4; ++mt){
    const short8 a0 = *(const short8*)(p_s + (mt*16+l15)*72 +      g*8);
    const short8 a1 = *(const short8*)(p_s + (mt*16+l15)*72 + 32 + g*8);
    #pragma unroll
    for (int nd=0; nd<2; ++nd){
      f32x4 o = __builtin_amdgcn_mfma_f32_16x16x32_bf16(a0, vf[nd][0], zf, 0, 0, 0);
      o = __builtin_amdgcn_mfma_f32_16x16x32_bf16(a1, vf[nd][1], o, 0, 0, 0);
      #pragma unroll
      for (int i=0;i<4;++i){
        const int q = mt*16 + g*4 + i;
        aout[(long)lidx[q]*192 + h*32 + nd*16 + l15] = f2b(o[i]);
      }
    }
  }
}

// ===================== kernels =============================================

// setup: ln1 (0..32767) | prep (32768..35362) | rpb+zero (35363)
__global__ __launch_bounds__(256) void setup_k(
    const float* __restrict__ x, const float* __restrict__ n1w,
    const float* __restrict__ n1b, u16* __restrict__ xn,
    const float* __restrict__ qkvw, const float* __restrict__ qb,
    const float* __restrict__ vb, const float* __restrict__ projw,
    const float* __restrict__ fc1w, const float* __restrict__ fc2w,
    const float* __restrict__ cab1w, const float* __restrict__ cab2w,
    const float* __restrict__ lgs,
    float* __restrict__ qkvbias, u16* __restrict__ wqkv, u16* __restrict__ wproj,
    u16* __restrict__ wfc1, u16* __restrict__ wfc2, u16* __restrict__ wt1,
    u16* __restrict__ wt2, float* __restrict__ scale6,
    const float* __restrict__ cpb1w, const float* __restrict__ cpb1b,
    const float* __restrict__ cpb2w, float* __restrict__ rpbL,
    float* __restrict__ ssum)
{
  __shared__ float hb[1350];
  const int bid = blockIdx.x, tid = threadIdx.x;
  if (bid < 32768){ ln_body(bid, tid, x, n1w, n1b, xn); return; }
  if (bid < 35363){
    prep_body(bid-32768, tid, qkvw, qb, vb, projw, fc1w, fc2w, cab1w, cab2w,
              lgs, qkvbias, wqkv, wproj, wfc1, wfc2, wt1, wt2, scale6);
    return;
  }
  rpb_body(tid, hb, cpb1w, cpb1b, cpb2w, rpbL, ssum);
}

// stage2: conv1 (0..511) | qkv (512..1535)
__global__ __launch_bounds__(256, 2) void stage2_k(
    const u16* __restrict__ xn, const u16* __restrict__ wt1,
    const float* __restrict__ cab1b, u16* __restrict__ g1,
    const u16* __restrict__ wqkv, const float* __restrict__ qkvbias,
    u16* __restrict__ qkvb)
{
  __shared__ __align__(16) char LDSU[128000];
  const int bid = blockIdx.x, tid = threadIdx.x;
  if (bid < 512)
    conv4_body<1,6,192,64,64,4,9>(LDSU, bid, 0, tid, xn, wt1, cab1b, g1, nullptr);
  else
    gemm4_body<192,576>(LDSU, bid-512, tid, xn, wqkv, qkvbias, qkvb);
}

// stage3: attn (0..3071) | conv2 (3072..4095)
__global__ __launch_bounds__(256, 2) void stage3_k(
    const u16* __restrict__ qkvb, const float* __restrict__ rpbL,
    const float* __restrict__ scale6, u16* __restrict__ ao,
    const u16* __restrict__ g1, const u16* __restrict__ wt2,
    const float* __restrict__ cab2b, u16* __restrict__ c2,
    float* __restrict__ ssum)
{
  __shared__ __align__(16) char LDSU[58176];
  const int bid = blockIdx.x, tid = threadIdx.x;
  if (bid < 3072)
    attn_body(LDSU, bid, tid, qkvb, rpbL, scale6, ao);
  else {
    const int b2 = bid - 3072;
    conv4_body<2,2,64,192,96,6,3>(LDSU, b2 & 511, b2 >> 9, tid, g1, wt2, cab2b, c2, ssum);
  }
}

// ------------- SE MLP ------------------------------------------------------
__global__ __launch_bounds__(256) void se_k(const float* __restrict__ ssum,
    const float* __restrict__ ca1w, const float* __restrict__ ca1b,
    const float* __restrict__ ca2w, const float* __restrict__ ca2b,
    float* __restrict__ sgate)
{
  __shared__ float hid[48];
  const int tid = threadIdx.x;
  if (tid < 48){
    int b = tid/6, cs = tid%6;
    float a = ca1b[cs];
    for (int c=0;c<192;++c) a += ssum[b*192+c]*(1.f/16384.f)*ca1w[cs*192+c];
    hid[tid] = fmaxf(a, 0.f);
  }
  __syncthreads();
  for (int o = tid; o < 1536; o += 256){
    int b = o/192, c = o%192;
    float a = ca2b[c];
    #pragma unroll
    for (int cs=0;cs<6;++cs) a += hid[b*6+cs]*ca2w[c*6+cs];
    sgate[o] = 1.f/(1.f+expf(-a));
  }
}

// ------------- proj_k: dout = ao@Wp^T + b + x + 0.01*c2*s ------------------
__global__ __launch_bounds__(256) void proj_k(
    const u16* __restrict__ A, const u16* __restrict__ W,
    const float* __restrict__ bias, const float* __restrict__ resx,
    const u16* __restrict__ c2in, const float* __restrict__ sgate,
    float* __restrict__ outf)
{
  __shared__ __align__(16) u16 As[64*200];
  const int tid = threadIdx.x, w = tid>>6, lane = tid&63;
  const int fr = lane&15, g = lane>>4;
  const int m0 = blockIdx.x*64;

  #pragma unroll
  for (int i=0;i<6;++i){ const int id=tid+i*256, r=id/24, cc=id%24;
    *(short8*)&As[r*200+cc*8] = *(const short8*)(A + (long)(m0+r)*192 + cc*8); }
  __syncthreads();

  f32x4 acc[12];
  #pragma unroll
  for (int n=0;n<12;++n) acc[n] = (f32x4){0.f,0.f,0.f,0.f};
  #pragma unroll
  for (int ks=0;ks<6;++ks){
    const short8 af = *(const short8*)&As[(w*16+fr)*200 + ks*32 + g*8];
    #pragma unroll
    for (int nr=0;nr<12;++nr){
      const short8 bf = *(const short8*)(W + ((nr*6+ks)*64 + lane)*8);
      acc[nr] = __builtin_amdgcn_mfma_f32_16x16x32_bf16(af, bf, acc[nr], 0,0,0);
    }
  }

  float* fbuf = (float*)As;
  #pragma unroll
  for (int ch=0;ch<2;++ch){
    __syncthreads();
    #pragma unroll
    for (int nr=0;nr<6;++nr){
      const float bc = bias[ch*96 + nr*16 + fr];
      #pragma unroll
      for (int i=0;i<4;++i)
        fbuf[(w*16+g*4+i)*100 + nr*16+fr] = acc[ch*6+nr][i] + bc;
    }
    __syncthreads();
    #pragma unroll
    for (int j=0;j<6;++j){
      const int idx = tid + j*256, t = idx/24, cc = idx%24;
      const int tokg = m0 + t, gc0 = ch*96 + cc*4;
      const long o = (long)tokg*192 + gc0;
      f32x4 v = *(const f32x4*)&fbuf[t*100 + cc*4];
      const f32x4 r = *(const f32x4*)(resx + o);
      const u16* cp = c2in + (long)ch*C2PLANE + (long)tokg*96 + cc*4;
      const float* sg = sgate + (tokg>>14)*192 + gc0;
      #pragma unroll
      for (int e=0;e<4;++e) v[e] += r[e] + 0.01f*b2f(cp[e])*sg[e];
      *(f32x4*)(outf + o) = v;
    }
  }
}

// ------------- mlp_k: r17 (single Hs, rcp-gelu, half-pass epilogue) --------
__global__ __launch_bounds__(256, 2) void mlp_k(
    const float* __restrict__ xio,
    const float* __restrict__ lw, const float* __restrict__ lb,
    const u16* __restrict__ w1, const float* __restrict__ b1,
    const u16* __restrict__ w2, const float* __restrict__ b2,
    float* __restrict__ out)
{
  __shared__ __align__(16) char SB[25600];
  const int tid = threadIdx.x, w = tid>>6, lane = tid&63;
  const int fr = lane&15, g = lane>>4;
  const int m0 = blockIdx.x*128;
  u16* hs = ((u16*)SB) + w*(32*72);

  short8 af[2][6];
  #pragma unroll
  for (int mr=0; mr<2; ++mr){
    const long r = (long)(m0 + w*32 + mr*16 + fr)*192;
    f32x4 v[6][2];
    float s = 0.f;
    #pragma unroll
    for (int ks=0; ks<6; ++ks){
      v[ks][0] = *(const f32x4*)(xio + r + ks*32 + g*8);
      v[ks][1] = *(const f32x4*)(xio + r + ks*32 + g*8 + 4);
      #pragma unroll
      for (int e=0;e<4;++e) s += v[ks][0][e] + v[ks][1][e];
    }
    s += __shfl_xor(s,16); s += __shfl_xor(s,32);
    const float mu = s*(1.0f/192.0f);
    float q = 0.f;
    #pragma unroll
    for (int ks=0; ks<6; ++ks)
      #pragma unroll
      for (int h=0;h<2;++h)
        #pragma unroll
        for (int e=0;e<4;++e){ const float d = v[ks][h][e]-mu; q += d*d; }
    q += __shfl_xor(q,16); q += __shfl_xor(q,32);
    const float rstd = rsqrtf(q*(1.0f/192.0f)+1e-5f);
    #pragma unroll
    for (int ks=0; ks<6; ++ks){
      const int c0 = ks*32 + g*8;
      #pragma unroll
      for (int h=0;h<2;++h)
        #pragma unroll
        for (int e=0;e<4;++e)
          af[mr][ks][h*4+e] =
            (short)f2b((v[ks][h][e]-mu)*rstd*lw[c0+h*4+e] + lb[c0+h*4+e]);
    }
  }

  f32x4 acc2[2][12];
  #pragma unroll
  for (int a=0;a<2;++a)
    #pragma unroll
    for (int n=0;n<12;++n) acc2[a][n] = (f32x4){0.f,0.f,0.f,0.f};

  for (int p=0; p<12; ++p){
    f32x4 a1[2][4];
    #pragma unroll
    for (int a=0;a<2;++a)
      #pragma unroll
      for (int n=0;n<4;++n) a1[a][n] = (f32x4){0.f,0.f,0.f,0.f};
    #pragma unroll
    for (int ks=0;ks<6;++ks){
      #pragma unroll
      for (int nr=0;nr<4;++nr){
        const short8 bf = *(const short8*)(w1 + ((((p*4+nr)*6+ks)<<6) + lane)*8);
        a1[0][nr] = __builtin_amdgcn_mfma_f32_16x16x32_bf16(af[0][ks], bf, a1[0][nr], 0,0,0);
        a1[1][nr] = __builtin_amdgcn_mfma_f32_16x16x32_bf16(af[1][ks], bf, a1[1][nr], 0,0,0);
      }
    }
    #pragma unroll
    for (int mr=0;mr<2;++mr)
      #pragma unroll
      for (int nr=0;nr<4;++nr){
        const float bc = b1[p*64 + nr*16 + fr];
        #pragma unroll
        for (int i=0;i<4;++i)
          hs[(mr*16+g*4+i)*72 + nr*16+fr] = f2b(gelu_f(a1[mr][nr][i] + bc));
      }
    #pragma unroll
    for (int ks2=0;ks2<2;++ks2){
      const short8 ah0 = *(const short8*)&hs[(fr   )*72 + ks2*32 + g*8];
      const short8 ah1 = *(const short8*)&hs[(16+fr)*72 + ks2*32 + g*8];
      #pragma unroll
      for (int nr2=0;nr2<12;++nr2){
        const short8 bf = *(const short8*)(w2 + ((((p*12+nr2)*2+ks2)<<6) + lane)*8);
        acc2[0][nr2] = __builtin_amdgcn_mfma_f32_16x16x32_bf16(ah0, bf, acc2[0][nr2], 0,0,0);
        acc2[1][nr2] = __builtin_amdgcn_mfma_f32_16x16x32_bf16(ah1, bf, acc2[1][nr2], 0,0,0);
      }
    }
  }

  float* fbuf = (float*)SB;
  #pragma unroll
  for (int hp=0; hp<2; ++hp){
    #pragma unroll
    for (int ch=0;ch<2;++ch){
      __syncthreads();
      if ((w>>1) == hp){
        #pragma unroll
        for (int mr=0;mr<2;++mr)
          #pragma unroll
          for (int nr=0;nr<6;++nr){
            const float bc = b2[ch*96 + nr*16 + fr];
            #pragma unroll
            for (int i=0;i<4;++i)
              fbuf[((w&1)*32+mr*16+g*4+i)*100 + nr*16+fr] = acc2[mr][ch*6+nr][i] + bc;
          }
      }
      __syncthreads();
      #pragma unroll
      for (int j=0;j<6;++j){
        const int idx = tid + j*256, t = idx/24, cc = idx%24;
        const long o = (long)(m0 + hp*64 + t)*192 + ch*96 + cc*4;
        f32x4 v = *(const f32x4*)&fbuf[t*100 + cc*4];
        const f32x4 r = *(const f32x4*)(xio + o);
        #pragma unroll
        for (int e=0;e<4;++e) v[e] += r[e];
        *(f32x4*)(out + o) = v;
      }
    }
  }
}

// ---------------------------------------------------------------------------
extern "C" void kernel_launch(void* const* d_in, const int* in_sizes, int n_in,
                              void* d_out, int out_size, void* d_ws, size_t ws_size,
                              hipStream_t stream)
{
  const float* x     = (const float*)d_in[0];
  const float* n1w   = (const float*)d_in[3];
  const float* n1b   = (const float*)d_in[4];
  const float* qkvw  = (const float*)d_in[5];
  const float* qb    = (const float*)d_in[6];
  const float* vb    = (const float*)d_in[7];
  const float* lgs   = (const float*)d_in[8];
  const float* cpb1w = (const float*)d_in[9];
  const float* cpb1b = (const float*)d_in[10];
  const float* cpb2w = (const float*)d_in[11];
  const float* projw = (const float*)d_in[12];
  const float* projb = (const float*)d_in[13];
  const float* cab1w = (const float*)d_in[14];
  const float* cab1b = (const float*)d_in[15];
  const float* cab2w = (const float*)d_in[16];
  const float* cab2b = (const float*)d_in[17];
  const float* ca1w  = (const float*)d_in[18];
  const float* ca1b  = (const float*)d_in[19];
  const float* ca2w  = (const float*)d_in[20];
  const float* ca2b  = (const float*)d_in[21];
  const float* n2w   = (const float*)d_in[22];
  const float* n2b   = (const float*)d_in[23];
  const float* fc1w  = (const float*)d_in[24];
  const float* fc1b  = (const float*)d_in[25];
  const float* fc2w  = (const float*)d_in[26];
  const float* fc2b  = (const float*)d_in[27];
  float* dout = (float*)d_out;
  char* ws = (char*)d_ws;

  constexpr size_t OFF_XN  = 0;
  constexpr size_t OFF_G1  = 50331648;
  constexpr size_t OFF_C2  = 67108864;
  constexpr size_t OFF_AO  = 167772160;
  constexpr size_t OFF_QKV = 218103808;
  constexpr size_t OFF_SM  = 369098752;

  u16*   xn      = (u16*)(ws + OFF_XN);
  u16*   g1      = (u16*)(ws + OFF_G1);
  u16*   c2      = (u16*)(ws + OFF_C2);
  u16*   ao      = (u16*)(ws + OFF_AO);
  u16*   qkvb    = (u16*)(ws + OFF_QKV);
  float* qkvbias = (float*)(ws + OFF_SM);
  float* scale6  = (float*)(ws + OFF_SM + 4096);
  float* ssum    = (float*)(ws + OFF_SM + 8192);
  float* sgate   = (float*)(ws + OFF_SM + 16384);
  float* rpbL    = (float*)(ws + OFF_SM + 24576);
  u16*   wqkv    = (u16*)(ws + OFF_SM + 131072);
  u16*   wproj   = (u16*)(ws + OFF_SM + 360448);
  u16*   wfc1    = (u16*)(ws + OFF_SM + 434176);
  u16*   wfc2    = (u16*)(ws + OFF_SM + 729088);
  u16*   wt1     = (u16*)(ws + OFF_SM + 1024000);
  u16*   wt2     = (u16*)(ws + OFF_SM + 1245184);

  setup_k<<<35364, 256, 0, stream>>>(x, n1w, n1b, xn,
      qkvw, qb, vb, projw, fc1w, fc2w, cab1w, cab2w, lgs,
      qkvbias, wqkv, wproj, wfc1, wfc2, wt1, wt2, scale6,
      cpb1w, cpb1b, cpb2w, rpbL, ssum);
  stage2_k<<<1536, 256, 0, stream>>>(xn, wt1, cab1b, g1, wqkv, qkvbias, qkvb);
  stage3_k<<<4096, 256, 0, stream>>>(qkvb, rpbL, scale6, ao, g1, wt2, cab2b, c2, ssum);
  se_k<<<1, 256, 0, stream>>>(ssum, ca1w, ca1b, ca2w, ca2b, sgate);
  proj_k<<<2048, 256, 0, stream>>>(ao, wproj, projb, x, c2, sgate, dout);
  mlp_k<<<1024, 256, 0, stream>>>(dout, n2w, n2b, wfc1, fc1b, wfc2, fc2b, dout);
}

// Round 19
// 801.607 us; speedup vs baseline: 1.0387x; 1.0387x over previous
//
#include <hip/hip_runtime.h>
#include <math.h>

// ---------------------------------------------------------------------------
// SwinV2-style block (DIM=192, HEADS=6, WS=8, SHIFT=4) on MI355X.
// Round 19: revert to r17 (best, 636us) + one corrected merge: stage2 =
// conv1 || qkv with union LDS 78,912B (2 blocks/CU for BOTH — r18's bug was
// a 128KB union -> 1 block/CU). attn/conv2/proj/mlp/setup all = r17.
// ---------------------------------------------------------------------------

typedef unsigned short u16;
typedef __attribute__((ext_vector_type(8))) short short8;
typedef __attribute__((ext_vector_type(4))) float f32x4;

#define DI static __device__ __forceinline__

DI float b2f(u16 u){ union{unsigned u; float f;} v; v.u = ((unsigned)u)<<16; return v.f; }
DI u16 f2b(float f){ union{float f; unsigned u;} v; v.f = f; unsigned r = v.u + 0x7fffu + ((v.u>>16)&1u); return (u16)(r>>16); }
// tanh-GELU with hardware rcp (no VCC-serialized division).
DI float gelu_f(float x){
  const float u = x*(0.7978845608f + 0.0356774081f*x*x);
  const float r = __builtin_amdgcn_rcpf(1.0f + __expf(2.0f*u));
  return x - x*r;
}

#define C2PLANE (12582912L)   // 131072*96

// ---------------- LayerNorm: f32 in -> bf16 out (row = 192 ch) -------------
__global__ __launch_bounds__(256) void ln_k(const float* __restrict__ in,
    const float* __restrict__ w, const float* __restrict__ b, u16* __restrict__ out)
{
  const int row  = blockIdx.x*4 + (threadIdx.x>>6);
  const int lane = threadIdx.x & 63;
  const float* r = in + (long)row*192;
  float v0 = r[lane], v1 = r[lane+64], v2 = r[lane+128];
  float s = v0+v1+v2;
  #pragma unroll
  for (int m=1;m<64;m<<=1) s += __shfl_xor(s, m);
  float mu = s*(1.0f/192.0f);
  float d0=v0-mu, d1=v1-mu, d2=v2-mu;
  float q = d0*d0+d1*d1+d2*d2;
  #pragma unroll
  for (int m=1;m<64;m<<=1) q += __shfl_xor(q, m);
  float rstd = rsqrtf(q*(1.0f/192.0f)+1e-5f);
  u16* o = out + (long)row*192;
  o[lane]     = f2b(d0*rstd*w[lane]    +b[lane]);
  o[lane+64]  = f2b(d1*rstd*w[lane+64] +b[lane+64]);
  o[lane+128] = f2b(d2*rstd*w[lane+128]+b[lane+128]);
}

// ------------- weight prep: f32->bf16, frag-packing, conv re-layout --------
__global__ __launch_bounds__(256) void prep_k(
    const float* __restrict__ qkv_w, const float* __restrict__ q_bias,
    const float* __restrict__ v_bias, const float* __restrict__ proj_w,
    const float* __restrict__ fc1_w, const float* __restrict__ fc2_w,
    const float* __restrict__ cab1_w, const float* __restrict__ cab2_w,
    const float* __restrict__ lgs,
    float* __restrict__ qkvbias, u16* __restrict__ wqkv, u16* __restrict__ wproj,
    u16* __restrict__ wfc1, u16* __restrict__ wfc2, u16* __restrict__ wt1,
    u16* __restrict__ wt2, float* __restrict__ scale6)
{
  int o = blockIdx.x*256 + threadIdx.x;
  if (o < 576){ qkvbias[o] = (o<192)? q_bias[o] : ((o<384)? 0.f : v_bias[o-384]); return; }
  o -= 576;
  if (o < 110592){ wqkv[o] = f2b(qkv_w[o]); return; } o -= 110592;
  if (o < 36864){ // wproj packed: [nr(12)][ks(6)][lane(64)][e(8)]
    const int e = o&7, lane = (o>>3)&63, ks = (o>>9)%6, nr = o/3072;
    const int row = nr*16 + (lane&15), col = ks*32 + (lane>>4)*8 + e;
    wproj[o] = f2b(proj_w[row*192 + col]); return; } o -= 36864;
  if (o < 147456){ // wfc1 packed: [p(12)][nr(4)][ks(6)][lane][e]
    const int e = o&7, lane = (o>>3)&63, ks = (o>>9)%6, rest = o/3072;
    const int nr = rest&3, p = rest>>2;
    const int row = p*64 + nr*16 + (lane&15), col = ks*32 + (lane>>4)*8 + e;
    wfc1[o] = f2b(fc1_w[row*192 + col]); return; } o -= 147456;
  if (o < 147456){ // wfc2 packed: [p(12)][nr2(12)][ks2(2)][lane][e]
    const int e = o&7, lane = (o>>3)&63, ks2 = (o>>9)&1, rest = o>>10;
    const int nr2 = rest%12, p = rest/12;
    const int row = nr2*16 + (lane&15);
    const int col = p*64 + ks2*32 + (lane>>4)*8 + e;
    wfc2[o] = f2b(fc2_w[row*768 + col]); return; } o -= 147456;
  if (o < 110592){ // wt1[s][oc(64)][ic(192)]
    int s = o/12288, r = o%12288, oc = r/192, ic = r%192, kh = s/3, kw = s%3;
    wt1[o] = f2b(cab1_w[((oc*192+ic)*3+kh)*3+kw]); return; } o -= 110592;
  if (o < 110592){ // wt2[s][oc(192)][ic(64)]
    int s = o/12288, r = o%12288, oc = r/64, ic = r%64, kh = s/3, kw = s%3;
    wt2[o] = f2b(cab2_w[((oc*64+ic)*3+kh)*3+kw]); return; } o -= 110592;
  if (o < 6){ scale6[o] = expf(fminf(lgs[o], logf(100.f))); }
}

// ---- CPB MLP -> rpbL in MFMA C-fragment order: [h][nQ][mK][lane][i] -------
__global__ __launch_bounds__(256) void rpb_k(const float* __restrict__ w1,
    const float* __restrict__ b1, const float* __restrict__ w2, float* __restrict__ rpbL)
{
  __shared__ float hb[225*6];
  const int tid = threadIdx.x;
  if (tid < 225){
    int di = tid/15, dj = tid%15;
    float vi = (di-7)*(8.0f/7.0f), vj = (dj-7)*(8.0f/7.0f);
    float t0 = (vi==0.f)?0.f:copysignf(log2f(fabsf(vi)+1.f)*(1.f/3.f), vi);
    float t1 = (vj==0.f)?0.f:copysignf(log2f(fabsf(vj)+1.f)*(1.f/3.f), vj);
    float acc[6] = {0,0,0,0,0,0};
    for (int hd=0; hd<512; ++hd){
      float a = fmaxf(t0*w1[hd*2] + t1*w1[hd*2+1] + b1[hd], 0.f);
      #pragma unroll
      for (int h=0;h<6;++h) acc[h] += a*w2[h*512+hd];
    }
    #pragma unroll
    for (int h=0;h<6;++h) hb[tid*6+h] = acc[h];
  }
  __syncthreads();
  for (int o = tid; o < 24576; o += 256){
    int i = o&3, lane = (o>>2)&63, mK = (o>>8)&3, nQ = (o>>10)&3, h = o>>12;
    int q = nQ*16 + (lane&15), k = mK*16 + (lane>>4)*4 + i;
    int idx = ((q>>3)-(k>>3)+7)*15 + ((q&7)-(k&7)+7);
    rpbL[o] = 16.0f/(1.0f+expf(-hb[idx*6+h]));
  }
}

// ---- gemm4 body (qkv): LDS layout As@0 (51200B) + Bs@51200 (25600B) ------
template<int KK, int NN>
DI void gemm4_body(char* LDSU, int bid, int tid,
    const u16* __restrict__ A, const u16* __restrict__ W,
    const float* __restrict__ bias, u16* __restrict__ outb)
{
  constexpr int NP = NN/64;
  u16* As = (u16*)LDSU;
  u16* Bs = (u16*)(LDSU + 51200);
  const int w = tid>>6, lane = tid&63;
  const int fr = lane&15, g = lane>>4;
  const int m0 = bid*128;
  u16* obuf = Bs;

  #pragma unroll
  for (int i=0;i<12;++i){ const int id=tid+i*256, row=id/24, cc=id%24;
    *(short8*)&As[row*200+cc*8] =
      *(const short8*)(A + (long)(m0+row)*KK + cc*8); }

  short8 breg[6];
  #define LOADB(p) { \
    _Pragma("unroll") \
    for (int i=0;i<6;++i){ const int id=tid+i*256, br=id/24, cc=id%24; \
      breg[i] = *(const short8*)(W + (long)((p)*64+br)*KK + cc*8); } }
  #define STOREB() { \
    _Pragma("unroll") \
    for (int i=0;i<6;++i){ const int id=tid+i*256, br=id/24, cc=id%24; \
      *(short8*)&Bs[br*200+cc*8] = breg[i]; } }

  LOADB(0);
  for (int p=0; p<NP; ++p){
    __syncthreads();
    STOREB();
    __syncthreads();
    if (p+1 < NP) LOADB(p+1);
    f32x4 acc[2][4];
    #pragma unroll
    for (int a=0;a<2;++a)
      #pragma unroll
      for (int b=0;b<4;++b) acc[a][b] = (f32x4){0.f,0.f,0.f,0.f};
    #pragma unroll
    for (int ks=0; ks<6; ++ks){
      short8 af0 = *(const short8*)&As[(w*32+   fr)*200 + ks*32 + g*8];
      short8 af1 = *(const short8*)&As[(w*32+16+fr)*200 + ks*32 + g*8];
      #pragma unroll
      for (int nr=0;nr<4;++nr){
        short8 bf = *(const short8*)&Bs[(nr*16+fr)*200 + ks*32 + g*8];
        acc[0][nr] = __builtin_amdgcn_mfma_f32_16x16x32_bf16(af0, bf, acc[0][nr], 0,0,0);
        acc[1][nr] = __builtin_amdgcn_mfma_f32_16x16x32_bf16(af1, bf, acc[1][nr], 0,0,0);
      } }
    __syncthreads();
    #pragma unroll
    for (int mr=0;mr<2;++mr)
      #pragma unroll
      for (int nr=0;nr<4;++nr){
        const float bc = bias[p*64+nr*16+fr];
        #pragma unroll
        for (int i=0;i<4;++i){
          const int tok = w*32+mr*16+g*4+i;
          obuf[tok*72 + nr*16+fr] = f2b(acc[mr][nr][i] + bc); } }
    __syncthreads();
    #pragma unroll
    for (int j=0;j<4;++j){
      const int idx = tid + j*256, tok = idx>>3, cc = idx&7;
      *(short8*)(outb + (long)(m0+tok)*NN + p*64 + cc*8) =
          *(const short8*)&obuf[tok*72 + cc*8]; }
  }
  #undef LOADB
  #undef STOREB
}

// ---- conv3x3 implicit GEMM body; LDS = Ah@0 (37440B) + Wl@37440 -----------
template<int EPI, int CG, int IC, int OCT, int OCP, int NR, int TG>
DI void conv4_body(char* LDSU, int bx, int by, int tid,
    const u16* __restrict__ A, const u16* __restrict__ Wt,
    const float* __restrict__ bias, u16* __restrict__ outb,
    float* __restrict__ ssum)
{
  constexpr int NTG = 9/TG, S = CG*NTG;
  constexpr int WN = (TG*OCP*4 + 255)/256;
  u16* Ah = (u16*)LDSU;
  u16* Wl = (u16*)(LDSU + 37440);
  const int w = tid>>6, lane = tid&63;
  const int fr = lane&15, g = lane>>4;
  const int b = bx>>6, y0 = (bx&63)*2;
  const int oc0 = by*OCP;
  const int wrow = w>>1, wcol = (w&1)*64;

  f32x4 acc[4][NR];
  #pragma unroll
  for (int a=0;a<4;++a)
    #pragma unroll
    for (int n=0;n<NR;++n) acc[a][n] = (f32x4){0.f,0.f,0.f,0.f};

  short8 hreg[8], wreg[WN];

  #define PRELOAD(s) { \
    const int cg_=(s)/NTG, tg_=(s)%NTG; \
    if (tg_==0){ \
      _Pragma("unroll") \
      for (int i=0;i<8;++i){ \
        const int id=tid+i*256, p=id>>9, x=(id>>2)&127, cc=id&3, y=y0+p-1; \
        short8 v={0,0,0,0,0,0,0,0}; \
        if ((unsigned)y<128u) \
          v = *(const short8*)(A + (long)((((b<<7)|y)<<7)|x)*IC + cg_*32 + cc*8); \
        hreg[i]=v; } } \
    _Pragma("unroll") \
    for (int i=0;i<WN;++i){ \
      const int id=tid+i*256; \
      if (id < TG*OCP*4){ \
        const int t=id/(OCP*4), r=id%(OCP*4), oc=r>>2, cc=r&3; \
        wreg[i] = *(const short8*)(Wt + \
            (long)((tg_*TG+t)*OCT + oc0 + oc)*IC + cg_*32 + cc*8); } } }

  #define STORE_STAGED(s) { \
    const int tg_=(s)%NTG; \
    if (tg_==0){ \
      _Pragma("unroll") \
      for (int i=0;i<8;++i){ \
        const int id=tid+i*256, p=id>>9, x=(id>>2)&127, cc=id&3; \
        *(short8*)&Ah[(p*130 + x + 1)*36 + cc*8] = hreg[i]; } \
      if (tid < 32){ \
        const int p=tid>>3, r=tid&7, col=(r>>2)?129:0, cc=r&3; \
        *(short8*)&Ah[(p*130 + col)*36 + cc*8] = (short8){0,0,0,0,0,0,0,0}; } } \
    _Pragma("unroll") \
    for (int i=0;i<WN;++i){ \
      const int id=tid+i*256; \
      if (id < TG*OCP*4){ \
        const int t=id/(OCP*4), r=id%(OCP*4), oc=r>>2, cc=r&3; \
        *(short8*)&Wl[(t*OCP+oc)*36 + cc*8] = wreg[i]; } } }

  #define COMPUTE(s) { \
    const int tg_=(s)%NTG; \
    _Pragma("unroll") \
    for (int t=0;t<TG;++t){ \
      const int tap=tg_*TG+t, dy=tap/3, dx=tap%3; \
      short8 bf[NR]; \
      _Pragma("unroll") \
      for (int nr=0;nr<NR;++nr) \
        bf[nr] = *(const short8*)&Wl[(t*OCP + nr*16 + fr)*36 + g*8]; \
      short8 af2[4]; \
      _Pragma("unroll") \
      for (int mr=0;mr<4;++mr) \
        af2[mr] = *(const short8*)&Ah[((wrow+dy)*130 + wcol + mr*16 + fr + dx)*36 + g*8]; \
      _Pragma("unroll") \
      for (int mr=0;mr<4;++mr) \
        _Pragma("unroll") \
        for (int nr=0;nr<NR;++nr) \
          acc[mr][nr] = __builtin_amdgcn_mfma_f32_16x16x32_bf16(af2[mr], bf[nr], acc[mr][nr], 0,0,0); } }

  PRELOAD(0);
  for (int s=0; s<S; ++s){
    __syncthreads();
    STORE_STAGED(s);
    __syncthreads();
    if (s+1 < S) PRELOAD(s+1);
    COMPUTE(s);
  }
  #undef PRELOAD
  #undef STORE_STAGED
  #undef COMPUTE

  if constexpr (EPI==2){
    #pragma unroll
    for (int nr=0;nr<NR;++nr){
      const float bc = bias[oc0 + nr*16 + fr];
      float s = 0.f;
      #pragma unroll
      for (int mr=0;mr<4;++mr)
        #pragma unroll
        for (int i=0;i<4;++i) s += acc[mr][nr][i] + bc;
      s += __shfl_xor(s,16); s += __shfl_xor(s,32);
      if (lane < 16) atomicAdd(&ssum[b*192 + oc0 + nr*16 + lane], s);
    }
  }

  u16* ob = Ah;
  const long tb = (long)(((b<<7)|y0)<<7);
  __syncthreads();
  if constexpr (EPI==1){
    #pragma unroll
    for (int mr=0;mr<4;++mr)
      #pragma unroll
      for (int nr=0;nr<NR;++nr){
        const float bc = bias[nr*16 + fr];
        #pragma unroll
        for (int i=0;i<4;++i){
          const int tok = wrow*128 + wcol + mr*16 + g*4 + i;
          ob[tok*72 + nr*16+fr] = f2b(gelu_f(acc[mr][nr][i] + bc));
        }
      }
    __syncthreads();
    #pragma unroll
    for (int j=0;j<8;++j){
      const int idx = tid + j*256, tok = idx>>3, cc = idx&7;
      *(short8*)(outb + (tb+tok)*OCP + cc*8) = *(const short8*)&ob[tok*72 + cc*8];
    }
  } else {
    const long pbase = (long)by*C2PLANE;
    #pragma unroll
    for (int h=0;h<2;++h){
      if (h) __syncthreads();
      if (wrow == h){
        #pragma unroll
        for (int mr=0;mr<4;++mr)
          #pragma unroll
          for (int nr=0;nr<NR;++nr){
            const float bc = bias[oc0 + nr*16 + fr];
            #pragma unroll
            for (int i=0;i<4;++i){
              const int tok = wcol + mr*16 + g*4 + i;
              ob[tok*104 + nr*16+fr] = f2b(acc[mr][nr][i] + bc);
            }
          }
      }
      __syncthreads();
      #pragma unroll
      for (int j=0;j<6;++j){
        const int idx = tid + j*256, t = idx/12, cc = idx%12;
        *(short8*)(outb + pbase + (tb + h*128 + t)*96 + cc*8) =
            *(const short8*)&ob[t*104 + cc*8];
      }
    }
  }
}

// ---- stage2: conv1 (0..511) || qkv (512..1535); union 78912B, 2 blk/CU ----
__global__ __launch_bounds__(256, 2) void stage2_k(
    const u16* __restrict__ xn, const u16* __restrict__ wt1,
    const float* __restrict__ cab1b, u16* __restrict__ g1,
    const u16* __restrict__ wqkv, const float* __restrict__ qkvbias,
    u16* __restrict__ qkvb)
{
  __shared__ __align__(16) char LDSU[78912];
  const int bid = blockIdx.x, tid = threadIdx.x;
  if (bid < 512)
    conv4_body<1,6,192,64,64,4,9>(LDSU, bid, 0, tid, xn, wt1, cab1b, g1, nullptr);
  else
    gemm4_body<192,576>(LDSU, bid-512, tid, xn, wqkv, qkvbias, qkvb);
}

// ---- conv2 standalone (58176B LDS, as r17) --------------------------------
__global__ __launch_bounds__(256, 2) void conv2_k(
    const u16* __restrict__ g1, const u16* __restrict__ wt2,
    const float* __restrict__ cab2b, u16* __restrict__ c2,
    float* __restrict__ ssum)
{
  __shared__ __align__(16) char LDSU[58176];
  conv4_body<2,2,64,192,96,6,3>(LDSU, blockIdx.x, blockIdx.y, threadIdx.x,
                                g1, wt2, cab2b, c2, ssum);
}

// ------------- SE MLP ------------------------------------------------------
__global__ __launch_bounds__(256) void se_k(const float* __restrict__ ssum,
    const float* __restrict__ ca1w, const float* __restrict__ ca1b,
    const float* __restrict__ ca2w, const float* __restrict__ ca2b,
    float* __restrict__ sgate)
{
  __shared__ float hid[48];
  const int tid = threadIdx.x;
  if (tid < 48){
    int b = tid/6, cs = tid%6;
    float a = ca1b[cs];
    for (int c=0;c<192;++c) a += ssum[b*192+c]*(1.f/16384.f)*ca1w[cs*192+c];
    hid[tid] = fmaxf(a, 0.f);
  }
  __syncthreads();
  for (int o = tid; o < 1536; o += 256){
    int b = o/192, c = o%192;
    float a = ca2b[c];
    #pragma unroll
    for (int cs=0;cs<6;++cs) a += hid[b*6+cs]*ca2w[c*6+cs];
    sgate[o] = 1.f/(1.f+expf(-a));
  }
}

// ---------- MFMA windowed attention (r17 standalone, 43008B LDS) -----------
__global__ __launch_bounds__(256) void attn_k(const u16* __restrict__ qkv,
    const float* __restrict__ rpbL, const float* __restrict__ scale6,
    u16* __restrict__ aout)
{
  __shared__ int  lidx_s[4][64];
  __shared__ char region_s[4][64];
  __shared__ __align__(16) u16 p_s[4][64*72];
  const int tid = threadIdx.x, w = tid>>6, lane = tid&63;
  const int task = blockIdx.x*4 + w;
  const int win = task/6, h = task - win*6;
  const int b = win>>8, wn = win&255, wy = wn>>4, wx = wn&15;
  {
    int i = lane>>3, j = lane&7;
    int hs = wy*8+i, ws = wx*8+j;
    lidx_s[w][lane] = (b<<14) | (((hs+4)&127)<<7) | ((ws+4)&127);
    int hb = hs<120?0:(hs<124?1:2), wb = ws<120?0:(ws<124?1:2);
    region_s[w][lane] = (char)(hb*3+wb);
  }
  __syncthreads();
  const int g = lane>>4, l15 = lane&15;
  const bool edge = (wy==15) || (wx==15);
  const float scl = scale6[h];
  const f32x4 zf = {0.f,0.f,0.f,0.f};

  short8 kf[4];
  #pragma unroll
  for (int mt=0; mt<4; ++mt){
    const long base = (long)lidx_s[w][mt*16+l15]*576 + 192 + h*32 + g*8;
    short8 r = *(const short8*)(qkv + base);
    float f[8]; float ss = 0.f;
    #pragma unroll
    for (int e=0;e<8;++e){ f[e] = b2f((u16)r[e]); ss += f[e]*f[e]; }
    ss += __shfl_xor(ss,16); ss += __shfl_xor(ss,32);
    const float inv = 1.0f/fmaxf(sqrtf(ss), 1e-12f);
    #pragma unroll
    for (int e=0;e<8;++e) kf[mt][e] = (short)f2b(f[e]*inv);
  }

  #pragma unroll
  for (int nt=0; nt<4; ++nt){
    short8 qf;
    {
      const long base = (long)lidx_s[w][nt*16+l15]*576 + h*32 + g*8;
      short8 r = *(const short8*)(qkv + base);
      float f[8]; float ss = 0.f;
      #pragma unroll
      for (int e=0;e<8;++e){ f[e] = b2f((u16)r[e]); ss += f[e]*f[e]; }
      ss += __shfl_xor(ss,16); ss += __shfl_xor(ss,32);
      const float inv = 1.0f/fmaxf(sqrtf(ss), 1e-12f);
      #pragma unroll
      for (int e=0;e<8;++e) qf[e] = (short)f2b(f[e]*inv);
    }
    f32x4 st[4];
    #pragma unroll
    for (int mt=0; mt<4; ++mt)
      st[mt] = __builtin_amdgcn_mfma_f32_16x16x32_bf16(kf[mt], qf, zf, 0, 0, 0);
    float lv[16];
    const float* rp = rpbL + ((h*4+nt)*4)*256 + lane*4;
    const int rq = edge ? region_s[w][nt*16+l15] : 0;
    #pragma unroll
    for (int mt=0; mt<4; ++mt){
      const f32x4 rb = *(const f32x4*)(rp + mt*256);
      #pragma unroll
      for (int i=0;i<4;++i){
        float v = st[mt][i]*scl + rb[i];
        if (edge && region_s[w][mt*16+g*4+i] != rq) v -= 100.0f;
        lv[mt*4+i] = v;
      }
    }
    float mx = lv[0];
    #pragma unroll
    for (int t=1;t<16;++t) mx = fmaxf(mx, lv[t]);
    mx = fmaxf(mx, __shfl_xor(mx,16)); mx = fmaxf(mx, __shfl_xor(mx,32));
    float sum = 0.f;
    #pragma unroll
    for (int t=0;t<16;++t){ lv[t] = __expf(lv[t]-mx); sum += lv[t]; }
    sum += __shfl_xor(sum,16); sum += __shfl_xor(sum,32);
    const float isum = 1.0f/sum;
    u16* pr = p_s[w] + (nt*16+l15)*72;
    #pragma unroll
    for (int mt=0; mt<4; ++mt){
      #pragma unroll
      for (int j=0;j<2;++j){
        unsigned lo = f2b(lv[mt*4+2*j]  *isum);
        unsigned hi = f2b(lv[mt*4+2*j+1]*isum);
        *(unsigned*)(pr + mt*16 + g*4 + 2*j) = lo | (hi<<16);
      }
    }
  }

  short8 vf[2][2];
  #pragma unroll
  for (int nd=0; nd<2; ++nd)
    #pragma unroll
    for (int kc=0; kc<2; ++kc)
      #pragma unroll
      for (int e=0;e<8;++e){
        const int tok = kc*32 + g*8 + e;
        vf[nd][kc][e] = (short)qkv[(long)lidx_s[w][tok]*576 + 384 + h*32 + nd*16 + l15];
      }

  __syncthreads();

  #pragma unroll
  for (int mt=0; mt<4; ++mt){
    const short8 a0 = *(const short8*)(p_s[w] + (mt*16+l15)*72 +      g*8);
    const short8 a1 = *(const short8*)(p_s[w] + (mt*16+l15)*72 + 32 + g*8);
    #pragma unroll
    for (int nd=0; nd<2; ++nd){
      f32x4 o = __builtin_amdgcn_mfma_f32_16x16x32_bf16(a0, vf[nd][0], zf, 0, 0, 0);
      o = __builtin_amdgcn_mfma_f32_16x16x32_bf16(a1, vf[nd][1], o, 0, 0, 0);
      #pragma unroll
      for (int i=0;i<4;++i){
        const int q = mt*16 + g*4 + i;
        aout[(long)lidx_s[w][q]*192 + h*32 + nd*16 + l15] = f2b(o[i]);
      }
    }
  }
}

// ------------- proj_k: dout = ao@Wp^T + b + x + 0.01*c2*s ------------------
__global__ __launch_bounds__(256) void proj_k(
    const u16* __restrict__ A, const u16* __restrict__ W,
    const float* __restrict__ bias, const float* __restrict__ resx,
    const u16* __restrict__ c2in, const float* __restrict__ sgate,
    float* __restrict__ outf)
{
  __shared__ __align__(16) u16 As[64*200];
  const int tid = threadIdx.x, w = tid>>6, lane = tid&63;
  const int fr = lane&15, g = lane>>4;
  const int m0 = blockIdx.x*64;

  #pragma unroll
  for (int i=0;i<6;++i){ const int id=tid+i*256, r=id/24, cc=id%24;
    *(short8*)&As[r*200+cc*8] = *(const short8*)(A + (long)(m0+r)*192 + cc*8); }
  __syncthreads();

  f32x4 acc[12];
  #pragma unroll
  for (int n=0;n<12;++n) acc[n] = (f32x4){0.f,0.f,0.f,0.f};
  #pragma unroll
  for (int ks=0;ks<6;++ks){
    const short8 af = *(const short8*)&As[(w*16+fr)*200 + ks*32 + g*8];
    #pragma unroll
    for (int nr=0;nr<12;++nr){
      const short8 bf = *(const short8*)(W + ((nr*6+ks)*64 + lane)*8);
      acc[nr] = __builtin_amdgcn_mfma_f32_16x16x32_bf16(af, bf, acc[nr], 0,0,0);
    }
  }

  float* fbuf = (float*)As;
  #pragma unroll
  for (int ch=0;ch<2;++ch){
    __syncthreads();
    #pragma unroll
    for (int nr=0;nr<6;++nr){
      const float bc = bias[ch*96 + nr*16 + fr];
      #pragma unroll
      for (int i=0;i<4;++i)
        fbuf[(w*16+g*4+i)*100 + nr*16+fr] = acc[ch*6+nr][i] + bc;
    }
    __syncthreads();
    #pragma unroll
    for (int j=0;j<6;++j){
      const int idx = tid + j*256, t = idx/24, cc = idx%24;
      const int tokg = m0 + t, gc0 = ch*96 + cc*4;
      const long o = (long)tokg*192 + gc0;
      f32x4 v = *(const f32x4*)&fbuf[t*100 + cc*4];
      const f32x4 r = *(const f32x4*)(resx + o);
      const u16* cp = c2in + (long)ch*C2PLANE + (long)tokg*96 + cc*4;
      const float* sg = sgate + (tokg>>14)*192 + gc0;
      #pragma unroll
      for (int e=0;e<4;++e) v[e] += r[e] + 0.01f*b2f(cp[e])*sg[e];
      *(f32x4*)(outf + o) = v;
    }
  }
}

// ------------- mlp_k: r17 (single Hs, rcp-gelu, half-pass epilogue) --------
__global__ __launch_bounds__(256, 2) void mlp_k(
    const float* __restrict__ xio,
    const float* __restrict__ lw, const float* __restrict__ lb,
    const u16* __restrict__ w1, const float* __restrict__ b1,
    const u16* __restrict__ w2, const float* __restrict__ b2,
    float* __restrict__ out)
{
  __shared__ __align__(16) char SB[25600];
  const int tid = threadIdx.x, w = tid>>6, lane = tid&63;
  const int fr = lane&15, g = lane>>4;
  const int m0 = blockIdx.x*128;
  u16* hs = ((u16*)SB) + w*(32*72);

  short8 af[2][6];
  #pragma unroll
  for (int mr=0; mr<2; ++mr){
    const long r = (long)(m0 + w*32 + mr*16 + fr)*192;
    f32x4 v[6][2];
    float s = 0.f;
    #pragma unroll
    for (int ks=0; ks<6; ++ks){
      v[ks][0] = *(const f32x4*)(xio + r + ks*32 + g*8);
      v[ks][1] = *(const f32x4*)(xio + r + ks*32 + g*8 + 4);
      #pragma unroll
      for (int e=0;e<4;++e) s += v[ks][0][e] + v[ks][1][e];
    }
    s += __shfl_xor(s,16); s += __shfl_xor(s,32);
    const float mu = s*(1.0f/192.0f);
    float q = 0.f;
    #pragma unroll
    for (int ks=0; ks<6; ++ks)
      #pragma unroll
      for (int h=0;h<2;++h)
        #pragma unroll
        for (int e=0;e<4;++e){ const float d = v[ks][h][e]-mu; q += d*d; }
    q += __shfl_xor(q,16); q += __shfl_xor(q,32);
    const float rstd = rsqrtf(q*(1.0f/192.0f)+1e-5f);
    #pragma unroll
    for (int ks=0; ks<6; ++ks){
      const int c0 = ks*32 + g*8;
      #pragma unroll
      for (int h=0;h<2;++h)
        #pragma unroll
        for (int e=0;e<4;++e)
          af[mr][ks][h*4+e] =
            (short)f2b((v[ks][h][e]-mu)*rstd*lw[c0+h*4+e] + lb[c0+h*4+e]);
    }
  }

  f32x4 acc2[2][12];
  #pragma unroll
  for (int a=0;a<2;++a)
    #pragma unroll
    for (int n=0;n<12;++n) acc2[a][n] = (f32x4){0.f,0.f,0.f,0.f};

  for (int p=0; p<12; ++p){
    f32x4 a1[2][4];
    #pragma unroll
    for (int a=0;a<2;++a)
      #pragma unroll
      for (int n=0;n<4;++n) a1[a][n] = (f32x4){0.f,0.f,0.f,0.f};
    #pragma unroll
    for (int ks=0;ks<6;++ks){
      #pragma unroll
      for (int nr=0;nr<4;++nr){
        const short8 bf = *(const short8*)(w1 + ((((p*4+nr)*6+ks)<<6) + lane)*8);
        a1[0][nr] = __builtin_amdgcn_mfma_f32_16x16x32_bf16(af[0][ks], bf, a1[0][nr], 0,0,0);
        a1[1][nr] = __builtin_amdgcn_mfma_f32_16x16x32_bf16(af[1][ks], bf, a1[1][nr], 0,0,0);
      }
    }
    #pragma unroll
    for (int mr=0;mr<2;++mr)
      #pragma unroll
      for (int nr=0;nr<4;++nr){
        const float bc = b1[p*64 + nr*16 + fr];
        #pragma unroll
        for (int i=0;i<4;++i)
          hs[(mr*16+g*4+i)*72 + nr*16+fr] = f2b(gelu_f(a1[mr][nr][i] + bc));
      }
    #pragma unroll
    for (int ks2=0;ks2<2;++ks2){
      const short8 ah0 = *(const short8*)&hs[(fr   )*72 + ks2*32 + g*8];
      const short8 ah1 = *(const short8*)&hs[(16+fr)*72 + ks2*32 + g*8];
      #pragma unroll
      for (int nr2=0;nr2<12;++nr2){
        const short8 bf = *(const short8*)(w2 + ((((p*12+nr2)*2+ks2)<<6) + lane)*8);
        acc2[0][nr2] = __builtin_amdgcn_mfma_f32_16x16x32_bf16(ah0, bf, acc2[0][nr2], 0,0,0);
        acc2[1][nr2] = __builtin_amdgcn_mfma_f32_16x16x32_bf16(ah1, bf, acc2[1][nr2], 0,0,0);
      }
    }
  }

  float* fbuf = (float*)SB;
  #pragma unroll
  for (int hp=0; hp<2; ++hp){
    #pragma unroll
    for (int ch=0;ch<2;++ch){
      __syncthreads();
      if ((w>>1) == hp){
        #pragma unroll
        for (int mr=0;mr<2;++mr)
          #pragma unroll
          for (int nr=0;nr<6;++nr){
            const float bc = b2[ch*96 + nr*16 + fr];
            #pragma unroll
            for (int i=0;i<4;++i)
              fbuf[((w&1)*32+mr*16+g*4+i)*100 + nr*16+fr] = acc2[mr][ch*6+nr][i] + bc;
          }
      }
      __syncthreads();
      #pragma unroll
      for (int j=0;j<6;++j){
        const int idx = tid + j*256, t = idx/24, cc = idx%24;
        const long o = (long)(m0 + hp*64 + t)*192 + ch*96 + cc*4;
        f32x4 v = *(const f32x4*)&fbuf[t*100 + cc*4];
        const f32x4 r = *(const f32x4*)(xio + o);
        #pragma unroll
        for (int e=0;e<4;++e) v[e] += r[e];
        *(f32x4*)(out + o) = v;
      }
    }
  }
}

// ---------------------------------------------------------------------------
extern "C" void kernel_launch(void* const* d_in, const int* in_sizes, int n_in,
                              void* d_out, int out_size, void* d_ws, size_t ws_size,
                              hipStream_t stream)
{
  const float* x     = (const float*)d_in[0];
  const float* n1w   = (const float*)d_in[3];
  const float* n1b   = (const float*)d_in[4];
  const float* qkvw  = (const float*)d_in[5];
  const float* qb    = (const float*)d_in[6];
  const float* vb    = (const float*)d_in[7];
  const float* lgs   = (const float*)d_in[8];
  const float* cpb1w = (const float*)d_in[9];
  const float* cpb1b = (const float*)d_in[10];
  const float* cpb2w = (const float*)d_in[11];
  const float* projw = (const float*)d_in[12];
  const float* projb = (const float*)d_in[13];
  const float* cab1w = (const float*)d_in[14];
  const float* cab1b = (const float*)d_in[15];
  const float* cab2w = (const float*)d_in[16];
  const float* cab2b = (const float*)d_in[17];
  const float* ca1w  = (const float*)d_in[18];
  const float* ca1b  = (const float*)d_in[19];
  const float* ca2w  = (const float*)d_in[20];
  const float* ca2b  = (const float*)d_in[21];
  const float* n2w   = (const float*)d_in[22];
  const float* n2b   = (const float*)d_in[23];
  const float* fc1w  = (const float*)d_in[24];
  const float* fc1b  = (const float*)d_in[25];
  const float* fc2w  = (const float*)d_in[26];
  const float* fc2b  = (const float*)d_in[27];
  float* dout = (float*)d_out;
  char* ws = (char*)d_ws;

  constexpr size_t OFF_XN  = 0;
  constexpr size_t OFF_G1  = 50331648;
  constexpr size_t OFF_C2  = 67108864;
  constexpr size_t OFF_AO  = 167772160;
  constexpr size_t OFF_QKV = 218103808;
  constexpr size_t OFF_SM  = 369098752;

  u16*   xn      = (u16*)(ws + OFF_XN);
  u16*   g1      = (u16*)(ws + OFF_G1);
  u16*   c2      = (u16*)(ws + OFF_C2);
  u16*   ao      = (u16*)(ws + OFF_AO);
  u16*   qkvb    = (u16*)(ws + OFF_QKV);
  float* qkvbias = (float*)(ws + OFF_SM);
  float* scale6  = (float*)(ws + OFF_SM + 4096);
  float* ssum    = (float*)(ws + OFF_SM + 8192);
  float* sgate   = (float*)(ws + OFF_SM + 16384);
  float* rpbL    = (float*)(ws + OFF_SM + 24576);
  u16*   wqkv    = (u16*)(ws + OFF_SM + 131072);
  u16*   wproj   = (u16*)(ws + OFF_SM + 360448);
  u16*   wfc1    = (u16*)(ws + OFF_SM + 434176);
  u16*   wfc2    = (u16*)(ws + OFF_SM + 729088);
  u16*   wt1     = (u16*)(ws + OFF_SM + 1024000);
  u16*   wt2     = (u16*)(ws + OFF_SM + 1245184);

  prep_k<<<2595, 256, 0, stream>>>(qkvw, qb, vb, projw, fc1w, fc2w, cab1w, cab2w,
                                   lgs, qkvbias, wqkv, wproj, wfc1, wfc2, wt1, wt2, scale6);
  rpb_k<<<1, 256, 0, stream>>>(cpb1w, cpb1b, cpb2w, rpbL);
  ln_k<<<32768, 256, 0, stream>>>(x, n1w, n1b, xn);
  hipMemsetAsync(ssum, 0, 1536*4, stream);
  stage2_k<<<1536, 256, 0, stream>>>(xn, wt1, cab1b, g1, wqkv, qkvbias, qkvb);
  conv2_k<<<dim3(512,2), 256, 0, stream>>>(g1, wt2, cab2b, c2, ssum);
  se_k<<<1, 256, 0, stream>>>(ssum, ca1w, ca1b, ca2w, ca2b, sgate);
  attn_k<<<3072, 256, 0, stream>>>(qkvb, rpbL, scale6, ao);
  proj_k<<<2048, 256, 0, stream>>>(ao, wproj, projb, x, c2, sgate, dout);
  mlp_k<<<1024, 256, 0, stream>>>(dout, n2w, n2b, wfc1, fc1b, wfc2, fc2b, dout);
}

// Round 20
// 635.770 us; speedup vs baseline: 1.3097x; 1.2608x over previous
//
#include <hip/hip_runtime.h>
#include <math.h>

// ---------------------------------------------------------------------------
// SwinV2-style block (DIM=192, HEADS=6, WS=8, SHIFT=4) on MI355X.
// Round 20: exact revert to round-17 (best measured: 636.8us).
// r18/r19 kernel-merge experiments both regressed (register allocation =
// max over merged bodies + constrained launch_bounds) and are discarded.
// ---------------------------------------------------------------------------

typedef unsigned short u16;
typedef __attribute__((ext_vector_type(8))) short short8;
typedef __attribute__((ext_vector_type(4))) float f32x4;

#define DI static __device__ __forceinline__

DI float b2f(u16 u){ union{unsigned u; float f;} v; v.u = ((unsigned)u)<<16; return v.f; }
DI u16 f2b(float f){ union{float f; unsigned u;} v; v.f = f; unsigned r = v.u + 0x7fffu + ((v.u>>16)&1u); return (u16)(r>>16); }
// tanh-GELU with hardware rcp (no VCC-serialized division).
DI float gelu_f(float x){
  const float u = x*(0.7978845608f + 0.0356774081f*x*x);
  const float r = __builtin_amdgcn_rcpf(1.0f + __expf(2.0f*u));
  return x - x*r;          // 0.5x(1+tanh(u)) = x - x/(1+e^{2u})
}

#define C2PLANE (12582912L)   // 131072*96

// ---------------- LayerNorm: f32 in -> bf16 out (row = 192 ch) -------------
__global__ __launch_bounds__(256) void ln_k(const float* __restrict__ in,
    const float* __restrict__ w, const float* __restrict__ b, u16* __restrict__ out)
{
  const int row  = blockIdx.x*4 + (threadIdx.x>>6);
  const int lane = threadIdx.x & 63;
  const float* r = in + (long)row*192;
  float v0 = r[lane], v1 = r[lane+64], v2 = r[lane+128];
  float s = v0+v1+v2;
  #pragma unroll
  for (int m=1;m<64;m<<=1) s += __shfl_xor(s, m);
  float mu = s*(1.0f/192.0f);
  float d0=v0-mu, d1=v1-mu, d2=v2-mu;
  float q = d0*d0+d1*d1+d2*d2;
  #pragma unroll
  for (int m=1;m<64;m<<=1) q += __shfl_xor(q, m);
  float rstd = rsqrtf(q*(1.0f/192.0f)+1e-5f);
  u16* o = out + (long)row*192;
  o[lane]     = f2b(d0*rstd*w[lane]    +b[lane]);
  o[lane+64]  = f2b(d1*rstd*w[lane+64] +b[lane+64]);
  o[lane+128] = f2b(d2*rstd*w[lane+128]+b[lane+128]);
}

// ------------- weight prep: f32->bf16, frag-packing, conv re-layout --------
__global__ __launch_bounds__(256) void prep_k(
    const float* __restrict__ qkv_w, const float* __restrict__ q_bias,
    const float* __restrict__ v_bias, const float* __restrict__ proj_w,
    const float* __restrict__ fc1_w, const float* __restrict__ fc2_w,
    const float* __restrict__ cab1_w, const float* __restrict__ cab2_w,
    const float* __restrict__ lgs,
    float* __restrict__ qkvbias, u16* __restrict__ wqkv, u16* __restrict__ wproj,
    u16* __restrict__ wfc1, u16* __restrict__ wfc2, u16* __restrict__ wt1,
    u16* __restrict__ wt2, float* __restrict__ scale6)
{
  int o = blockIdx.x*256 + threadIdx.x;
  if (o < 576){ qkvbias[o] = (o<192)? q_bias[o] : ((o<384)? 0.f : v_bias[o-384]); return; }
  o -= 576;
  if (o < 110592){ wqkv[o] = f2b(qkv_w[o]); return; } o -= 110592;
  if (o < 36864){ // wproj packed: [nr(12)][ks(6)][lane(64)][e(8)]
    const int e = o&7, lane = (o>>3)&63, ks = (o>>9)%6, nr = o/3072;
    const int row = nr*16 + (lane&15), col = ks*32 + (lane>>4)*8 + e;
    wproj[o] = f2b(proj_w[row*192 + col]); return; } o -= 36864;
  if (o < 147456){ // wfc1 packed: [p(12)][nr(4)][ks(6)][lane][e]
    const int e = o&7, lane = (o>>3)&63, ks = (o>>9)%6, rest = o/3072;
    const int nr = rest&3, p = rest>>2;
    const int row = p*64 + nr*16 + (lane&15), col = ks*32 + (lane>>4)*8 + e;
    wfc1[o] = f2b(fc1_w[row*192 + col]); return; } o -= 147456;
  if (o < 147456){ // wfc2 packed: [p(12)][nr2(12)][ks2(2)][lane][e]
    const int e = o&7, lane = (o>>3)&63, ks2 = (o>>9)&1, rest = o>>10;
    const int nr2 = rest%12, p = rest/12;
    const int row = nr2*16 + (lane&15);
    const int col = p*64 + ks2*32 + (lane>>4)*8 + e;
    wfc2[o] = f2b(fc2_w[row*768 + col]); return; } o -= 147456;
  if (o < 110592){ // wt1[s][oc(64)][ic(192)]
    int s = o/12288, r = o%12288, oc = r/192, ic = r%192, kh = s/3, kw = s%3;
    wt1[o] = f2b(cab1_w[((oc*192+ic)*3+kh)*3+kw]); return; } o -= 110592;
  if (o < 110592){ // wt2[s][oc(192)][ic(64)]
    int s = o/12288, r = o%12288, oc = r/64, ic = r%64, kh = s/3, kw = s%3;
    wt2[o] = f2b(cab2_w[((oc*64+ic)*3+kh)*3+kw]); return; } o -= 110592;
  if (o < 6){ scale6[o] = expf(fminf(lgs[o], logf(100.f))); }
}

// ---- CPB MLP -> rpbL in MFMA C-fragment order: [h][nQ][mK][lane][i] -------
__global__ __launch_bounds__(256) void rpb_k(const float* __restrict__ w1,
    const float* __restrict__ b1, const float* __restrict__ w2, float* __restrict__ rpbL)
{
  __shared__ float hb[225*6];
  const int tid = threadIdx.x;
  if (tid < 225){
    int di = tid/15, dj = tid%15;
    float vi = (di-7)*(8.0f/7.0f), vj = (dj-7)*(8.0f/7.0f);
    float t0 = (vi==0.f)?0.f:copysignf(log2f(fabsf(vi)+1.f)*(1.f/3.f), vi);
    float t1 = (vj==0.f)?0.f:copysignf(log2f(fabsf(vj)+1.f)*(1.f/3.f), vj);
    float acc[6] = {0,0,0,0,0,0};
    for (int hd=0; hd<512; ++hd){
      float a = fmaxf(t0*w1[hd*2] + t1*w1[hd*2+1] + b1[hd], 0.f);
      #pragma unroll
      for (int h=0;h<6;++h) acc[h] += a*w2[h*512+hd];
    }
    #pragma unroll
    for (int h=0;h<6;++h) hb[tid*6+h] = acc[h];
  }
  __syncthreads();
  for (int o = tid; o < 24576; o += 256){
    int i = o&3, lane = (o>>2)&63, mK = (o>>8)&3, nQ = (o>>10)&3, h = o>>12;
    int q = nQ*16 + (lane&15), k = mK*16 + (lane>>4)*4 + i;
    int idx = ((q>>3)-(k>>3)+7)*15 + ((q&7)-(k&7)+7);
    rpbL[o] = 16.0f/(1.0f+expf(-hb[idx*6+h]));
  }
}

// ---------------- gemm4 (qkv only): out = A @ W^T --------------------------
template<int EPI, int KK, int NN>
__global__ __launch_bounds__(256) void gemm4_k(
    const u16* __restrict__ A, const u16* __restrict__ W,
    const float* __restrict__ bias, u16* __restrict__ outb)
{
  constexpr int NP = NN/64;
  __shared__ __align__(16) u16 As[128*200];
  __shared__ __align__(16) u16 Bs[64*200];
  const int tid = threadIdx.x, w = tid>>6, lane = tid&63;
  const int fr = lane&15, g = lane>>4;
  const int m0 = blockIdx.x*128;
  u16* obuf = Bs;

  #pragma unroll
  for (int i=0;i<12;++i){ const int id=tid+i*256, row=id/24, cc=id%24;
    *(short8*)&As[row*200+cc*8] =
      *(const short8*)(A + (long)(m0+row)*KK + cc*8); }

  short8 breg[6];
  #define LOADB(p) { \
    _Pragma("unroll") \
    for (int i=0;i<6;++i){ const int id=tid+i*256, br=id/24, cc=id%24; \
      breg[i] = *(const short8*)(W + (long)((p)*64+br)*KK + cc*8); } }
  #define STOREB() { \
    _Pragma("unroll") \
    for (int i=0;i<6;++i){ const int id=tid+i*256, br=id/24, cc=id%24; \
      *(short8*)&Bs[br*200+cc*8] = breg[i]; } }

  LOADB(0);
  for (int p=0; p<NP; ++p){
    __syncthreads();
    STOREB();
    __syncthreads();
    if (p+1 < NP) LOADB(p+1);
    f32x4 acc[2][4];
    #pragma unroll
    for (int a=0;a<2;++a)
      #pragma unroll
      for (int b=0;b<4;++b) acc[a][b] = (f32x4){0.f,0.f,0.f,0.f};
    #pragma unroll
    for (int ks=0; ks<6; ++ks){
      short8 af0 = *(const short8*)&As[(w*32+   fr)*200 + ks*32 + g*8];
      short8 af1 = *(const short8*)&As[(w*32+16+fr)*200 + ks*32 + g*8];
      #pragma unroll
      for (int nr=0;nr<4;++nr){
        short8 bf = *(const short8*)&Bs[(nr*16+fr)*200 + ks*32 + g*8];
        acc[0][nr] = __builtin_amdgcn_mfma_f32_16x16x32_bf16(af0, bf, acc[0][nr], 0,0,0);
        acc[1][nr] = __builtin_amdgcn_mfma_f32_16x16x32_bf16(af1, bf, acc[1][nr], 0,0,0);
      } }
    __syncthreads();
    #pragma unroll
    for (int mr=0;mr<2;++mr)
      #pragma unroll
      for (int nr=0;nr<4;++nr){
        const float bc = bias[p*64+nr*16+fr];
        #pragma unroll
        for (int i=0;i<4;++i){
          const int tok = w*32+mr*16+g*4+i;
          obuf[tok*72 + nr*16+fr] = f2b(acc[mr][nr][i] + bc); } }
    __syncthreads();
    #pragma unroll
    for (int j=0;j<4;++j){
      const int idx = tid + j*256, tok = idx>>3, cc = idx&7;
      *(short8*)(outb + (long)(m0+tok)*NN + p*64 + cc*8) =
          *(const short8*)&obuf[tok*72 + cc*8]; }
  }
  #undef LOADB
  #undef STOREB
}

// ------------- proj_k (r11 form): dout = ao@Wp^T + b + x + 0.01*c2*s -------
__global__ __launch_bounds__(256) void proj_k(
    const u16* __restrict__ A, const u16* __restrict__ W,
    const float* __restrict__ bias, const float* __restrict__ resx,
    const u16* __restrict__ c2in, const float* __restrict__ sgate,
    float* __restrict__ outf)
{
  __shared__ __align__(16) u16 As[64*200];
  const int tid = threadIdx.x, w = tid>>6, lane = tid&63;
  const int fr = lane&15, g = lane>>4;
  const int m0 = blockIdx.x*64;

  #pragma unroll
  for (int i=0;i<6;++i){ const int id=tid+i*256, r=id/24, cc=id%24;
    *(short8*)&As[r*200+cc*8] = *(const short8*)(A + (long)(m0+r)*192 + cc*8); }
  __syncthreads();

  f32x4 acc[12];
  #pragma unroll
  for (int n=0;n<12;++n) acc[n] = (f32x4){0.f,0.f,0.f,0.f};
  #pragma unroll
  for (int ks=0;ks<6;++ks){
    const short8 af = *(const short8*)&As[(w*16+fr)*200 + ks*32 + g*8];
    #pragma unroll
    for (int nr=0;nr<12;++nr){
      const short8 bf = *(const short8*)(W + ((nr*6+ks)*64 + lane)*8);
      acc[nr] = __builtin_amdgcn_mfma_f32_16x16x32_bf16(af, bf, acc[nr], 0,0,0);
    }
  }

  float* fbuf = (float*)As;
  #pragma unroll
  for (int ch=0;ch<2;++ch){
    __syncthreads();
    #pragma unroll
    for (int nr=0;nr<6;++nr){
      const float bc = bias[ch*96 + nr*16 + fr];
      #pragma unroll
      for (int i=0;i<4;++i)
        fbuf[(w*16+g*4+i)*100 + nr*16+fr] = acc[ch*6+nr][i] + bc;
    }
    __syncthreads();
    #pragma unroll
    for (int j=0;j<6;++j){
      const int idx = tid + j*256, t = idx/24, cc = idx%24;
      const int tokg = m0 + t, gc0 = ch*96 + cc*4;
      const long o = (long)tokg*192 + gc0;
      f32x4 v = *(const f32x4*)&fbuf[t*100 + cc*4];
      const f32x4 r = *(const f32x4*)(resx + o);
      const u16* cp = c2in + (long)ch*C2PLANE + (long)tokg*96 + cc*4;
      const float* sg = sgate + (tokg>>14)*192 + gc0;
      #pragma unroll
      for (int e=0;e<4;++e) v[e] += r[e] + 0.01f*b2f(cp[e])*sg[e];
      *(f32x4*)(outf + o) = v;
    }
  }
}

// ------------- mlp_k: r16 structure, rcp-gelu ------------------------------
__global__ __launch_bounds__(256, 2) void mlp_k(
    const float* __restrict__ xio,
    const float* __restrict__ lw, const float* __restrict__ lb,
    const u16* __restrict__ w1, const float* __restrict__ b1,
    const u16* __restrict__ w2, const float* __restrict__ b2,
    float* __restrict__ out)
{
  __shared__ __align__(16) char SB[25600];      // union: Hs[4][32*72]u16 / fbuf 64x100 f32
  const int tid = threadIdx.x, w = tid>>6, lane = tid&63;
  const int fr = lane&15, g = lane>>4;
  const int m0 = blockIdx.x*128;
  u16* hs = ((u16*)SB) + w*(32*72);             // wave-private 4.6KB

  // ---- LN in registers -> A-frags ----
  short8 af[2][6];
  #pragma unroll
  for (int mr=0; mr<2; ++mr){
    const long r = (long)(m0 + w*32 + mr*16 + fr)*192;
    f32x4 v[6][2];
    float s = 0.f;
    #pragma unroll
    for (int ks=0; ks<6; ++ks){
      v[ks][0] = *(const f32x4*)(xio + r + ks*32 + g*8);
      v[ks][1] = *(const f32x4*)(xio + r + ks*32 + g*8 + 4);
      #pragma unroll
      for (int e=0;e<4;++e) s += v[ks][0][e] + v[ks][1][e];
    }
    s += __shfl_xor(s,16); s += __shfl_xor(s,32);
    const float mu = s*(1.0f/192.0f);
    float q = 0.f;
    #pragma unroll
    for (int ks=0; ks<6; ++ks)
      #pragma unroll
      for (int h=0;h<2;++h)
        #pragma unroll
        for (int e=0;e<4;++e){ const float d = v[ks][h][e]-mu; q += d*d; }
    q += __shfl_xor(q,16); q += __shfl_xor(q,32);
    const float rstd = rsqrtf(q*(1.0f/192.0f)+1e-5f);
    #pragma unroll
    for (int ks=0; ks<6; ++ks){
      const int c0 = ks*32 + g*8;
      #pragma unroll
      for (int h=0;h<2;++h)
        #pragma unroll
        for (int e=0;e<4;++e)
          af[mr][ks][h*4+e] =
            (short)f2b((v[ks][h][e]-mu)*rstd*lw[c0+h*4+e] + lb[c0+h*4+e]);
    }
  }

  f32x4 acc2[2][12];
  #pragma unroll
  for (int a=0;a<2;++a)
    #pragma unroll
    for (int n=0;n<12;++n) acc2[a][n] = (f32x4){0.f,0.f,0.f,0.f};

  for (int p=0; p<12; ++p){            // NO barriers inside
    // fc1: 32 rows x 64 h-cols, packed-burst B
    f32x4 a1[2][4];
    #pragma unroll
    for (int a=0;a<2;++a)
      #pragma unroll
      for (int n=0;n<4;++n) a1[a][n] = (f32x4){0.f,0.f,0.f,0.f};
    #pragma unroll
    for (int ks=0;ks<6;++ks){
      #pragma unroll
      for (int nr=0;nr<4;++nr){
        const short8 bf = *(const short8*)(w1 + ((((p*4+nr)*6+ks)<<6) + lane)*8);
        a1[0][nr] = __builtin_amdgcn_mfma_f32_16x16x32_bf16(af[0][ks], bf, a1[0][nr], 0,0,0);
        a1[1][nr] = __builtin_amdgcn_mfma_f32_16x16x32_bf16(af[1][ks], bf, a1[1][nr], 0,0,0);
      }
    }
    // rcp-gelu -> wave-private Hs (32 rows x 64 cols, stride 72)
    #pragma unroll
    for (int mr=0;mr<2;++mr)
      #pragma unroll
      for (int nr=0;nr<4;++nr){
        const float bc = b1[p*64 + nr*16 + fr];
        #pragma unroll
        for (int i=0;i<4;++i)
          hs[(mr*16+g*4+i)*72 + nr*16+fr] = f2b(gelu_f(a1[mr][nr][i] + bc));
      }
    // fc2 partial
    #pragma unroll
    for (int ks2=0;ks2<2;++ks2){
      const short8 ah0 = *(const short8*)&hs[(fr   )*72 + ks2*32 + g*8];
      const short8 ah1 = *(const short8*)&hs[(16+fr)*72 + ks2*32 + g*8];
      #pragma unroll
      for (int nr2=0;nr2<12;++nr2){
        const short8 bf = *(const short8*)(w2 + ((((p*12+nr2)*2+ks2)<<6) + lane)*8);
        acc2[0][nr2] = __builtin_amdgcn_mfma_f32_16x16x32_bf16(ah0, bf, acc2[0][nr2], 0,0,0);
        acc2[1][nr2] = __builtin_amdgcn_mfma_f32_16x16x32_bf16(ah1, bf, acc2[1][nr2], 0,0,0);
      }
    }
  }

  // ---- epilogue: out = xio + acc2 + b2; 64-token half-passes via LDS ----
  float* fbuf = (float*)SB;
  #pragma unroll
  for (int hp=0; hp<2; ++hp){
    #pragma unroll
    for (int ch=0;ch<2;++ch){
      __syncthreads();                 // retires Hs reads (first) / fbuf reads
      if ((w>>1) == hp){
        #pragma unroll
        for (int mr=0;mr<2;++mr)
          #pragma unroll
          for (int nr=0;nr<6;++nr){
            const float bc = b2[ch*96 + nr*16 + fr];
            #pragma unroll
            for (int i=0;i<4;++i)
              fbuf[((w&1)*32+mr*16+g*4+i)*100 + nr*16+fr] = acc2[mr][ch*6+nr][i] + bc;
          }
      }
      __syncthreads();
      #pragma unroll
      for (int j=0;j<6;++j){
        const int idx = tid + j*256, t = idx/24, cc = idx%24;
        const long o = (long)(m0 + hp*64 + t)*192 + ch*96 + cc*4;
        f32x4 v = *(const f32x4*)&fbuf[t*100 + cc*4];
        const f32x4 r = *(const f32x4*)(xio + o);
        #pragma unroll
        for (int e=0;e<4;++e) v[e] += r[e];
        *(f32x4*)(out + o) = v;
      }
    }
  }
}

// ------- conv3x3 implicit GEMM v4 (rcp-gelu) -------------------------------
template<int EPI, int CG, int IC, int OCT, int OCP, int NR, int TG>
__global__ __launch_bounds__(256, 2) void conv4_k(
    const u16* __restrict__ A, const u16* __restrict__ Wt,
    const float* __restrict__ bias, u16* __restrict__ outb,
    float* __restrict__ ssum)
{
  constexpr int NTG = 9/TG, S = CG*NTG;
  constexpr int WN = (TG*OCP*4 + 255)/256;
  __shared__ __align__(16) u16 Ah[4*130*36];
  __shared__ __align__(16) u16 Wl[TG*OCP*36];
  const int tid = threadIdx.x, w = tid>>6, lane = tid&63;
  const int fr = lane&15, g = lane>>4;
  const int b = blockIdx.x>>6, y0 = (blockIdx.x&63)*2;
  const int oc0 = blockIdx.y*OCP;
  const int wrow = w>>1, wcol = (w&1)*64;

  f32x4 acc[4][NR];
  #pragma unroll
  for (int a=0;a<4;++a)
    #pragma unroll
    for (int n=0;n<NR;++n) acc[a][n] = (f32x4){0.f,0.f,0.f,0.f};

  short8 hreg[8], wreg[WN];

  #define PRELOAD(s) { \
    const int cg_=(s)/NTG, tg_=(s)%NTG; \
    if (tg_==0){ \
      _Pragma("unroll") \
      for (int i=0;i<8;++i){ \
        const int id=tid+i*256, p=id>>9, x=(id>>2)&127, cc=id&3, y=y0+p-1; \
        short8 v={0,0,0,0,0,0,0,0}; \
        if ((unsigned)y<128u) \
          v = *(const short8*)(A + (long)((((b<<7)|y)<<7)|x)*IC + cg_*32 + cc*8); \
        hreg[i]=v; } } \
    _Pragma("unroll") \
    for (int i=0;i<WN;++i){ \
      const int id=tid+i*256; \
      if (id < TG*OCP*4){ \
        const int t=id/(OCP*4), r=id%(OCP*4), oc=r>>2, cc=r&3; \
        wreg[i] = *(const short8*)(Wt + \
            (long)((tg_*TG+t)*OCT + oc0 + oc)*IC + cg_*32 + cc*8); } } }

  #define STORE_STAGED(s) { \
    const int tg_=(s)%NTG; \
    if (tg_==0){ \
      _Pragma("unroll") \
      for (int i=0;i<8;++i){ \
        const int id=tid+i*256, p=id>>9, x=(id>>2)&127, cc=id&3; \
        *(short8*)&Ah[(p*130 + x + 1)*36 + cc*8] = hreg[i]; } \
      if (tid < 32){ \
        const int p=tid>>3, r=tid&7, col=(r>>2)?129:0, cc=r&3; \
        *(short8*)&Ah[(p*130 + col)*36 + cc*8] = (short8){0,0,0,0,0,0,0,0}; } } \
    _Pragma("unroll") \
    for (int i=0;i<WN;++i){ \
      const int id=tid+i*256; \
      if (id < TG*OCP*4){ \
        const int t=id/(OCP*4), r=id%(OCP*4), oc=r>>2, cc=r&3; \
        *(short8*)&Wl[(t*OCP+oc)*36 + cc*8] = wreg[i]; } } }

  #define COMPUTE(s) { \
    const int tg_=(s)%NTG; \
    _Pragma("unroll") \
    for (int t=0;t<TG;++t){ \
      const int tap=tg_*TG+t, dy=tap/3, dx=tap%3; \
      short8 bf[NR]; \
      _Pragma("unroll") \
      for (int nr=0;nr<NR;++nr) \
        bf[nr] = *(const short8*)&Wl[(t*OCP + nr*16 + fr)*36 + g*8]; \
      short8 af2[4]; \
      _Pragma("unroll") \
      for (int mr=0;mr<4;++mr) \
        af2[mr] = *(const short8*)&Ah[((wrow+dy)*130 + wcol + mr*16 + fr + dx)*36 + g*8]; \
      _Pragma("unroll") \
      for (int mr=0;mr<4;++mr) \
        _Pragma("unroll") \
        for (int nr=0;nr<NR;++nr) \
          acc[mr][nr] = __builtin_amdgcn_mfma_f32_16x16x32_bf16(af2[mr], bf[nr], acc[mr][nr], 0,0,0); } }

  PRELOAD(0);
  for (int s=0; s<S; ++s){
    __syncthreads();
    STORE_STAGED(s);
    __syncthreads();
    if (s+1 < S) PRELOAD(s+1);
    COMPUTE(s);
  }
  #undef PRELOAD
  #undef STORE_STAGED
  #undef COMPUTE

  if constexpr (EPI==2){
    #pragma unroll
    for (int nr=0;nr<NR;++nr){
      const float bc = bias[oc0 + nr*16 + fr];
      float s = 0.f;
      #pragma unroll
      for (int mr=0;mr<4;++mr)
        #pragma unroll
        for (int i=0;i<4;++i) s += acc[mr][nr][i] + bc;
      s += __shfl_xor(s,16); s += __shfl_xor(s,32);
      if (lane < 16) atomicAdd(&ssum[b*192 + oc0 + nr*16 + lane], s);
    }
  }

  u16* ob = Ah;
  const long tb = (long)(((b<<7)|y0)<<7);
  __syncthreads();
  if constexpr (EPI==1){
    #pragma unroll
    for (int mr=0;mr<4;++mr)
      #pragma unroll
      for (int nr=0;nr<NR;++nr){
        const float bc = bias[nr*16 + fr];
        #pragma unroll
        for (int i=0;i<4;++i){
          const int tok = wrow*128 + wcol + mr*16 + g*4 + i;
          ob[tok*72 + nr*16+fr] = f2b(gelu_f(acc[mr][nr][i] + bc));
        }
      }
    __syncthreads();
    #pragma unroll
    for (int j=0;j<8;++j){
      const int idx = tid + j*256, tok = idx>>3, cc = idx&7;
      *(short8*)(outb + (tb+tok)*OCP + cc*8) = *(const short8*)&ob[tok*72 + cc*8];
    }
  } else {
    const long pbase = (long)blockIdx.y*C2PLANE;
    #pragma unroll
    for (int h=0;h<2;++h){
      if (h) __syncthreads();
      if (wrow == h){
        #pragma unroll
        for (int mr=0;mr<4;++mr)
          #pragma unroll
          for (int nr=0;nr<NR;++nr){
            const float bc = bias[oc0 + nr*16 + fr];
            #pragma unroll
            for (int i=0;i<4;++i){
              const int tok = wcol + mr*16 + g*4 + i;
              ob[tok*104 + nr*16+fr] = f2b(acc[mr][nr][i] + bc);
            }
          }
      }
      __syncthreads();
      #pragma unroll
      for (int j=0;j<6;++j){
        const int idx = tid + j*256, t = idx/12, cc = idx%12;
        *(short8*)(outb + pbase + (tb + h*128 + t)*96 + cc*8) =
            *(const short8*)&ob[t*104 + cc*8];
      }
    }
  }
}

// ------------- SE MLP ------------------------------------------------------
__global__ __launch_bounds__(256) void se_k(const float* __restrict__ ssum,
    const float* __restrict__ ca1w, const float* __restrict__ ca1b,
    const float* __restrict__ ca2w, const float* __restrict__ ca2b,
    float* __restrict__ sgate)
{
  __shared__ float hid[48];
  const int tid = threadIdx.x;
  if (tid < 48){
    int b = tid/6, cs = tid%6;
    float a = ca1b[cs];
    for (int c=0;c<192;++c) a += ssum[b*192+c]*(1.f/16384.f)*ca1w[cs*192+c];
    hid[tid] = fmaxf(a, 0.f);
  }
  __syncthreads();
  for (int o = tid; o < 1536; o += 256){
    int b = o/192, c = o%192;
    float a = ca2b[c];
    #pragma unroll
    for (int cs=0;cs<6;++cs) a += hid[b*6+cs]*ca2w[c*6+cs];
    sgate[o] = 1.f/(1.f+expf(-a));
  }
}

// ---------- MFMA windowed attention: 1 wave = 1 (window, head) -------------
__global__ __launch_bounds__(256) void attn_k(const u16* __restrict__ qkv,
    const float* __restrict__ rpbL, const float* __restrict__ scale6,
    u16* __restrict__ aout)
{
  __shared__ int  lidx_s[4][64];
  __shared__ char region_s[4][64];
  __shared__ __align__(16) u16 p_s[4][64*72];
  const int tid = threadIdx.x, w = tid>>6, lane = tid&63;
  const int task = blockIdx.x*4 + w;
  const int win = task/6, h = task - win*6;
  const int b = win>>8, wn = win&255, wy = wn>>4, wx = wn&15;
  {
    int i = lane>>3, j = lane&7;
    int hs = wy*8+i, ws = wx*8+j;
    lidx_s[w][lane] = (b<<14) | (((hs+4)&127)<<7) | ((ws+4)&127);
    int hb = hs<120?0:(hs<124?1:2), wb = ws<120?0:(ws<124?1:2);
    region_s[w][lane] = (char)(hb*3+wb);
  }
  __syncthreads();
  const int g = lane>>4, l15 = lane&15;
  const bool edge = (wy==15) || (wx==15);
  const float scl = scale6[h];
  const f32x4 zf = {0.f,0.f,0.f,0.f};

  short8 kf[4];
  #pragma unroll
  for (int mt=0; mt<4; ++mt){
    const long base = (long)lidx_s[w][mt*16+l15]*576 + 192 + h*32 + g*8;
    short8 r = *(const short8*)(qkv + base);
    float f[8]; float ss = 0.f;
    #pragma unroll
    for (int e=0;e<8;++e){ f[e] = b2f((u16)r[e]); ss += f[e]*f[e]; }
    ss += __shfl_xor(ss,16); ss += __shfl_xor(ss,32);
    const float inv = 1.0f/fmaxf(sqrtf(ss), 1e-12f);
    #pragma unroll
    for (int e=0;e<8;++e) kf[mt][e] = (short)f2b(f[e]*inv);
  }

  #pragma unroll
  for (int nt=0; nt<4; ++nt){
    short8 qf;
    {
      const long base = (long)lidx_s[w][nt*16+l15]*576 + h*32 + g*8;
      short8 r = *(const short8*)(qkv + base);
      float f[8]; float ss = 0.f;
      #pragma unroll
      for (int e=0;e<8;++e){ f[e] = b2f((u16)r[e]); ss += f[e]*f[e]; }
      ss += __shfl_xor(ss,16); ss += __shfl_xor(ss,32);
      const float inv = 1.0f/fmaxf(sqrtf(ss), 1e-12f);
      #pragma unroll
      for (int e=0;e<8;++e) qf[e] = (short)f2b(f[e]*inv);
    }
    f32x4 st[4];
    #pragma unroll
    for (int mt=0; mt<4; ++mt)
      st[mt] = __builtin_amdgcn_mfma_f32_16x16x32_bf16(kf[mt], qf, zf, 0, 0, 0);
    float lv[16];
    const float* rp = rpbL + ((h*4+nt)*4)*256 + lane*4;
    const int rq = edge ? region_s[w][nt*16+l15] : 0;
    #pragma unroll
    for (int mt=0; mt<4; ++mt){
      const f32x4 rb = *(const f32x4*)(rp + mt*256);
      #pragma unroll
      for (int i=0;i<4;++i){
        float v = st[mt][i]*scl + rb[i];
        if (edge && region_s[w][mt*16+g*4+i] != rq) v -= 100.0f;
        lv[mt*4+i] = v;
      }
    }
    float mx = lv[0];
    #pragma unroll
    for (int t=1;t<16;++t) mx = fmaxf(mx, lv[t]);
    mx = fmaxf(mx, __shfl_xor(mx,16)); mx = fmaxf(mx, __shfl_xor(mx,32));
    float sum = 0.f;
    #pragma unroll
    for (int t=0;t<16;++t){ lv[t] = __expf(lv[t]-mx); sum += lv[t]; }
    sum += __shfl_xor(sum,16); sum += __shfl_xor(sum,32);
    const float isum = 1.0f/sum;
    u16* pr = p_s[w] + (nt*16+l15)*72;
    #pragma unroll
    for (int mt=0; mt<4; ++mt){
      #pragma unroll
      for (int j=0;j<2;++j){
        unsigned lo = f2b(lv[mt*4+2*j]  *isum);
        unsigned hi = f2b(lv[mt*4+2*j+1]*isum);
        *(unsigned*)(pr + mt*16 + g*4 + 2*j) = lo | (hi<<16);
      }
    }
  }

  short8 vf[2][2];
  #pragma unroll
  for (int nd=0; nd<2; ++nd)
    #pragma unroll
    for (int kc=0; kc<2; ++kc)
      #pragma unroll
      for (int e=0;e<8;++e){
        const int tok = kc*32 + g*8 + e;
        vf[nd][kc][e] = (short)qkv[(long)lidx_s[w][tok]*576 + 384 + h*32 + nd*16 + l15];
      }

  __syncthreads();

  #pragma unroll
  for (int mt=0; mt<4; ++mt){
    const short8 a0 = *(const short8*)(p_s[w] + (mt*16+l15)*72 +      g*8);
    const short8 a1 = *(const short8*)(p_s[w] + (mt*16+l15)*72 + 32 + g*8);
    #pragma unroll
    for (int nd=0; nd<2; ++nd){
      f32x4 o = __builtin_amdgcn_mfma_f32_16x16x32_bf16(a0, vf[nd][0], zf, 0, 0, 0);
      o = __builtin_amdgcn_mfma_f32_16x16x32_bf16(a1, vf[nd][1], o, 0, 0, 0);
      #pragma unroll
      for (int i=0;i<4;++i){
        const int q = mt*16 + g*4 + i;
        aout[(long)lidx_s[w][q]*192 + h*32 + nd*16 + l15] = f2b(o[i]);
      }
    }
  }
}

// ---------------------------------------------------------------------------
extern "C" void kernel_launch(void* const* d_in, const int* in_sizes, int n_in,
                              void* d_out, int out_size, void* d_ws, size_t ws_size,
                              hipStream_t stream)
{
  const float* x     = (const float*)d_in[0];
  const float* n1w   = (const float*)d_in[3];
  const float* n1b   = (const float*)d_in[4];
  const float* qkvw  = (const float*)d_in[5];
  const float* qb    = (const float*)d_in[6];
  const float* vb    = (const float*)d_in[7];
  const float* lgs   = (const float*)d_in[8];
  const float* cpb1w = (const float*)d_in[9];
  const float* cpb1b = (const float*)d_in[10];
  const float* cpb2w = (const float*)d_in[11];
  const float* projw = (const float*)d_in[12];
  const float* projb = (const float*)d_in[13];
  const float* cab1w = (const float*)d_in[14];
  const float* cab1b = (const float*)d_in[15];
  const float* cab2w = (const float*)d_in[16];
  const float* cab2b = (const float*)d_in[17];
  const float* ca1w  = (const float*)d_in[18];
  const float* ca1b  = (const float*)d_in[19];
  const float* ca2w  = (const float*)d_in[20];
  const float* ca2b  = (const float*)d_in[21];
  const float* n2w   = (const float*)d_in[22];
  const float* n2b   = (const float*)d_in[23];
  const float* fc1w  = (const float*)d_in[24];
  const float* fc1b  = (const float*)d_in[25];
  const float* fc2w  = (const float*)d_in[26];
  const float* fc2b  = (const float*)d_in[27];
  float* dout = (float*)d_out;
  char* ws = (char*)d_ws;

  constexpr size_t OFF_XN  = 0;
  constexpr size_t OFF_G1  = 50331648;
  constexpr size_t OFF_C2  = 67108864;
  constexpr size_t OFF_AO  = 167772160;
  constexpr size_t OFF_QKV = 218103808;
  constexpr size_t OFF_SM  = 369098752;

  u16*   xn      = (u16*)(ws + OFF_XN);
  u16*   g1      = (u16*)(ws + OFF_G1);
  u16*   c2      = (u16*)(ws + OFF_C2);
  u16*   ao      = (u16*)(ws + OFF_AO);
  u16*   qkvb    = (u16*)(ws + OFF_QKV);
  float* qkvbias = (float*)(ws + OFF_SM);
  float* scale6  = (float*)(ws + OFF_SM + 4096);
  float* ssum    = (float*)(ws + OFF_SM + 8192);
  float* sgate   = (float*)(ws + OFF_SM + 16384);
  float* rpbL    = (float*)(ws + OFF_SM + 24576);
  u16*   wqkv    = (u16*)(ws + OFF_SM + 131072);
  u16*   wproj   = (u16*)(ws + OFF_SM + 360448);
  u16*   wfc1    = (u16*)(ws + OFF_SM + 434176);
  u16*   wfc2    = (u16*)(ws + OFF_SM + 729088);
  u16*   wt1     = (u16*)(ws + OFF_SM + 1024000);
  u16*   wt2     = (u16*)(ws + OFF_SM + 1245184);

  prep_k<<<2595, 256, 0, stream>>>(qkvw, qb, vb, projw, fc1w, fc2w, cab1w, cab2w,
                                   lgs, qkvbias, wqkv, wproj, wfc1, wfc2, wt1, wt2, scale6);
  rpb_k<<<1, 256, 0, stream>>>(cpb1w, cpb1b, cpb2w, rpbL);
  ln_k<<<32768, 256, 0, stream>>>(x, n1w, n1b, xn);
  hipMemsetAsync(ssum, 0, 1536*4, stream);
  conv4_k<1,6,192,64,64,4,9><<<dim3(512,1), 256, 0, stream>>>(xn, wt1, cab1b, g1, nullptr);
  conv4_k<2,2,64,192,96,6,3><<<dim3(512,2), 256, 0, stream>>>(g1, wt2, cab2b, c2, ssum);
  se_k<<<1, 256, 0, stream>>>(ssum, ca1w, ca1b, ca2w, ca2b, sgate);
  gemm4_k<0,192,576><<<1024, 256, 0, stream>>>(xn, wqkv, qkvbias, qkvb);
  attn_k<<<3072, 256, 0, stream>>>(qkvb, rpbL, scale6, ao);
  proj_k<<<2048, 256, 0, stream>>>(ao, wproj, projb, x, c2, sgate, dout);
  mlp_k<<<1024, 256, 0, stream>>>(dout, n2w, n2b, wfc1, fc1b, wfc2, fc2b, dout);
}

// Round 21
// 628.206 us; speedup vs baseline: 1.3254x; 1.0120x over previous
//
#include <hip/hip_runtime.h>
#include <math.h>

// ---------------------------------------------------------------------------
// SwinV2-style block (DIM=192, HEADS=6, WS=8, SHIFT=4) on MI355X.
// Round 21: r20 (best, 635.8us) + two zero-risk micro-levers:
//  (a) attn_k barriers removed — all its LDS is wave-private (lidx_s[w],
//      region_s[w], p_s[w]), so block-wide lockstep was pure overhead;
//  (b) ssum zeroing folded into rpb_k, memset launch dropped.
// ---------------------------------------------------------------------------

typedef unsigned short u16;
typedef __attribute__((ext_vector_type(8))) short short8;
typedef __attribute__((ext_vector_type(4))) float f32x4;

#define DI static __device__ __forceinline__

DI float b2f(u16 u){ union{unsigned u; float f;} v; v.u = ((unsigned)u)<<16; return v.f; }
DI u16 f2b(float f){ union{float f; unsigned u;} v; v.f = f; unsigned r = v.u + 0x7fffu + ((v.u>>16)&1u); return (u16)(r>>16); }
// tanh-GELU with hardware rcp (no VCC-serialized division).
DI float gelu_f(float x){
  const float u = x*(0.7978845608f + 0.0356774081f*x*x);
  const float r = __builtin_amdgcn_rcpf(1.0f + __expf(2.0f*u));
  return x - x*r;          // 0.5x(1+tanh(u)) = x - x/(1+e^{2u})
}

#define C2PLANE (12582912L)   // 131072*96

// ---------------- LayerNorm: f32 in -> bf16 out (row = 192 ch) -------------
__global__ __launch_bounds__(256) void ln_k(const float* __restrict__ in,
    const float* __restrict__ w, const float* __restrict__ b, u16* __restrict__ out)
{
  const int row  = blockIdx.x*4 + (threadIdx.x>>6);
  const int lane = threadIdx.x & 63;
  const float* r = in + (long)row*192;
  float v0 = r[lane], v1 = r[lane+64], v2 = r[lane+128];
  float s = v0+v1+v2;
  #pragma unroll
  for (int m=1;m<64;m<<=1) s += __shfl_xor(s, m);
  float mu = s*(1.0f/192.0f);
  float d0=v0-mu, d1=v1-mu, d2=v2-mu;
  float q = d0*d0+d1*d1+d2*d2;
  #pragma unroll
  for (int m=1;m<64;m<<=1) q += __shfl_xor(q, m);
  float rstd = rsqrtf(q*(1.0f/192.0f)+1e-5f);
  u16* o = out + (long)row*192;
  o[lane]     = f2b(d0*rstd*w[lane]    +b[lane]);
  o[lane+64]  = f2b(d1*rstd*w[lane+64] +b[lane+64]);
  o[lane+128] = f2b(d2*rstd*w[lane+128]+b[lane+128]);
}

// ------------- weight prep: f32->bf16, frag-packing, conv re-layout --------
__global__ __launch_bounds__(256) void prep_k(
    const float* __restrict__ qkv_w, const float* __restrict__ q_bias,
    const float* __restrict__ v_bias, const float* __restrict__ proj_w,
    const float* __restrict__ fc1_w, const float* __restrict__ fc2_w,
    const float* __restrict__ cab1_w, const float* __restrict__ cab2_w,
    const float* __restrict__ lgs,
    float* __restrict__ qkvbias, u16* __restrict__ wqkv, u16* __restrict__ wproj,
    u16* __restrict__ wfc1, u16* __restrict__ wfc2, u16* __restrict__ wt1,
    u16* __restrict__ wt2, float* __restrict__ scale6)
{
  int o = blockIdx.x*256 + threadIdx.x;
  if (o < 576){ qkvbias[o] = (o<192)? q_bias[o] : ((o<384)? 0.f : v_bias[o-384]); return; }
  o -= 576;
  if (o < 110592){ wqkv[o] = f2b(qkv_w[o]); return; } o -= 110592;
  if (o < 36864){ // wproj packed: [nr(12)][ks(6)][lane(64)][e(8)]
    const int e = o&7, lane = (o>>3)&63, ks = (o>>9)%6, nr = o/3072;
    const int row = nr*16 + (lane&15), col = ks*32 + (lane>>4)*8 + e;
    wproj[o] = f2b(proj_w[row*192 + col]); return; } o -= 36864;
  if (o < 147456){ // wfc1 packed: [p(12)][nr(4)][ks(6)][lane][e]
    const int e = o&7, lane = (o>>3)&63, ks = (o>>9)%6, rest = o/3072;
    const int nr = rest&3, p = rest>>2;
    const int row = p*64 + nr*16 + (lane&15), col = ks*32 + (lane>>4)*8 + e;
    wfc1[o] = f2b(fc1_w[row*192 + col]); return; } o -= 147456;
  if (o < 147456){ // wfc2 packed: [p(12)][nr2(12)][ks2(2)][lane][e]
    const int e = o&7, lane = (o>>3)&63, ks2 = (o>>9)&1, rest = o>>10;
    const int nr2 = rest%12, p = rest/12;
    const int row = nr2*16 + (lane&15);
    const int col = p*64 + ks2*32 + (lane>>4)*8 + e;
    wfc2[o] = f2b(fc2_w[row*768 + col]); return; } o -= 147456;
  if (o < 110592){ // wt1[s][oc(64)][ic(192)]
    int s = o/12288, r = o%12288, oc = r/192, ic = r%192, kh = s/3, kw = s%3;
    wt1[o] = f2b(cab1_w[((oc*192+ic)*3+kh)*3+kw]); return; } o -= 110592;
  if (o < 110592){ // wt2[s][oc(192)][ic(64)]
    int s = o/12288, r = o%12288, oc = r/64, ic = r%64, kh = s/3, kw = s%3;
    wt2[o] = f2b(cab2_w[((oc*64+ic)*3+kh)*3+kw]); return; } o -= 110592;
  if (o < 6){ scale6[o] = expf(fminf(lgs[o], logf(100.f))); }
}

// ---- CPB MLP -> rpbL (+ ssum zeroing) -------------------------------------
__global__ __launch_bounds__(256) void rpb_k(const float* __restrict__ w1,
    const float* __restrict__ b1, const float* __restrict__ w2,
    float* __restrict__ rpbL, float* __restrict__ ssum)
{
  __shared__ float hb[225*6];
  const int tid = threadIdx.x;
  for (int i=tid; i<1536; i+=256) ssum[i] = 0.f;
  if (tid < 225){
    int di = tid/15, dj = tid%15;
    float vi = (di-7)*(8.0f/7.0f), vj = (dj-7)*(8.0f/7.0f);
    float t0 = (vi==0.f)?0.f:copysignf(log2f(fabsf(vi)+1.f)*(1.f/3.f), vi);
    float t1 = (vj==0.f)?0.f:copysignf(log2f(fabsf(vj)+1.f)*(1.f/3.f), vj);
    float acc[6] = {0,0,0,0,0,0};
    for (int hd=0; hd<512; ++hd){
      float a = fmaxf(t0*w1[hd*2] + t1*w1[hd*2+1] + b1[hd], 0.f);
      #pragma unroll
      for (int h=0;h<6;++h) acc[h] += a*w2[h*512+hd];
    }
    #pragma unroll
    for (int h=0;h<6;++h) hb[tid*6+h] = acc[h];
  }
  __syncthreads();
  for (int o = tid; o < 24576; o += 256){
    int i = o&3, lane = (o>>2)&63, mK = (o>>8)&3, nQ = (o>>10)&3, h = o>>12;
    int q = nQ*16 + (lane&15), k = mK*16 + (lane>>4)*4 + i;
    int idx = ((q>>3)-(k>>3)+7)*15 + ((q&7)-(k&7)+7);
    rpbL[o] = 16.0f/(1.0f+expf(-hb[idx*6+h]));
  }
}

// ---------------- gemm4 (qkv only): out = A @ W^T --------------------------
template<int EPI, int KK, int NN>
__global__ __launch_bounds__(256) void gemm4_k(
    const u16* __restrict__ A, const u16* __restrict__ W,
    const float* __restrict__ bias, u16* __restrict__ outb)
{
  constexpr int NP = NN/64;
  __shared__ __align__(16) u16 As[128*200];
  __shared__ __align__(16) u16 Bs[64*200];
  const int tid = threadIdx.x, w = tid>>6, lane = tid&63;
  const int fr = lane&15, g = lane>>4;
  const int m0 = blockIdx.x*128;
  u16* obuf = Bs;

  #pragma unroll
  for (int i=0;i<12;++i){ const int id=tid+i*256, row=id/24, cc=id%24;
    *(short8*)&As[row*200+cc*8] =
      *(const short8*)(A + (long)(m0+row)*KK + cc*8); }

  short8 breg[6];
  #define LOADB(p) { \
    _Pragma("unroll") \
    for (int i=0;i<6;++i){ const int id=tid+i*256, br=id/24, cc=id%24; \
      breg[i] = *(const short8*)(W + (long)((p)*64+br)*KK + cc*8); } }
  #define STOREB() { \
    _Pragma("unroll") \
    for (int i=0;i<6;++i){ const int id=tid+i*256, br=id/24, cc=id%24; \
      *(short8*)&Bs[br*200+cc*8] = breg[i]; } }

  LOADB(0);
  for (int p=0; p<NP; ++p){
    __syncthreads();
    STOREB();
    __syncthreads();
    if (p+1 < NP) LOADB(p+1);
    f32x4 acc[2][4];
    #pragma unroll
    for (int a=0;a<2;++a)
      #pragma unroll
      for (int b=0;b<4;++b) acc[a][b] = (f32x4){0.f,0.f,0.f,0.f};
    #pragma unroll
    for (int ks=0; ks<6; ++ks){
      short8 af0 = *(const short8*)&As[(w*32+   fr)*200 + ks*32 + g*8];
      short8 af1 = *(const short8*)&As[(w*32+16+fr)*200 + ks*32 + g*8];
      #pragma unroll
      for (int nr=0;nr<4;++nr){
        short8 bf = *(const short8*)&Bs[(nr*16+fr)*200 + ks*32 + g*8];
        acc[0][nr] = __builtin_amdgcn_mfma_f32_16x16x32_bf16(af0, bf, acc[0][nr], 0,0,0);
        acc[1][nr] = __builtin_amdgcn_mfma_f32_16x16x32_bf16(af1, bf, acc[1][nr], 0,0,0);
      } }
    __syncthreads();
    #pragma unroll
    for (int mr=0;mr<2;++mr)
      #pragma unroll
      for (int nr=0;nr<4;++nr){
        const float bc = bias[p*64+nr*16+fr];
        #pragma unroll
        for (int i=0;i<4;++i){
          const int tok = w*32+mr*16+g*4+i;
          obuf[tok*72 + nr*16+fr] = f2b(acc[mr][nr][i] + bc); } }
    __syncthreads();
    #pragma unroll
    for (int j=0;j<4;++j){
      const int idx = tid + j*256, tok = idx>>3, cc = idx&7;
      *(short8*)(outb + (long)(m0+tok)*NN + p*64 + cc*8) =
          *(const short8*)&obuf[tok*72 + cc*8]; }
  }
  #undef LOADB
  #undef STOREB
}

// ------------- proj_k (r11 form): dout = ao@Wp^T + b + x + 0.01*c2*s -------
__global__ __launch_bounds__(256) void proj_k(
    const u16* __restrict__ A, const u16* __restrict__ W,
    const float* __restrict__ bias, const float* __restrict__ resx,
    const u16* __restrict__ c2in, const float* __restrict__ sgate,
    float* __restrict__ outf)
{
  __shared__ __align__(16) u16 As[64*200];
  const int tid = threadIdx.x, w = tid>>6, lane = tid&63;
  const int fr = lane&15, g = lane>>4;
  const int m0 = blockIdx.x*64;

  #pragma unroll
  for (int i=0;i<6;++i){ const int id=tid+i*256, r=id/24, cc=id%24;
    *(short8*)&As[r*200+cc*8] = *(const short8*)(A + (long)(m0+r)*192 + cc*8); }
  __syncthreads();

  f32x4 acc[12];
  #pragma unroll
  for (int n=0;n<12;++n) acc[n] = (f32x4){0.f,0.f,0.f,0.f};
  #pragma unroll
  for (int ks=0;ks<6;++ks){
    const short8 af = *(const short8*)&As[(w*16+fr)*200 + ks*32 + g*8];
    #pragma unroll
    for (int nr=0;nr<12;++nr){
      const short8 bf = *(const short8*)(W + ((nr*6+ks)*64 + lane)*8);
      acc[nr] = __builtin_amdgcn_mfma_f32_16x16x32_bf16(af, bf, acc[nr], 0,0,0);
    }
  }

  float* fbuf = (float*)As;
  #pragma unroll
  for (int ch=0;ch<2;++ch){
    __syncthreads();
    #pragma unroll
    for (int nr=0;nr<6;++nr){
      const float bc = bias[ch*96 + nr*16 + fr];
      #pragma unroll
      for (int i=0;i<4;++i)
        fbuf[(w*16+g*4+i)*100 + nr*16+fr] = acc[ch*6+nr][i] + bc;
    }
    __syncthreads();
    #pragma unroll
    for (int j=0;j<6;++j){
      const int idx = tid + j*256, t = idx/24, cc = idx%24;
      const int tokg = m0 + t, gc0 = ch*96 + cc*4;
      const long o = (long)tokg*192 + gc0;
      f32x4 v = *(const f32x4*)&fbuf[t*100 + cc*4];
      const f32x4 r = *(const f32x4*)(resx + o);
      const u16* cp = c2in + (long)ch*C2PLANE + (long)tokg*96 + cc*4;
      const float* sg = sgate + (tokg>>14)*192 + gc0;
      #pragma unroll
      for (int e=0;e<4;++e) v[e] += r[e] + 0.01f*b2f(cp[e])*sg[e];
      *(f32x4*)(outf + o) = v;
    }
  }
}

// ------------- mlp_k: r16 structure, rcp-gelu ------------------------------
__global__ __launch_bounds__(256, 2) void mlp_k(
    const float* __restrict__ xio,
    const float* __restrict__ lw, const float* __restrict__ lb,
    const u16* __restrict__ w1, const float* __restrict__ b1,
    const u16* __restrict__ w2, const float* __restrict__ b2,
    float* __restrict__ out)
{
  __shared__ __align__(16) char SB[25600];      // union: Hs[4][32*72]u16 / fbuf 64x100 f32
  const int tid = threadIdx.x, w = tid>>6, lane = tid&63;
  const int fr = lane&15, g = lane>>4;
  const int m0 = blockIdx.x*128;
  u16* hs = ((u16*)SB) + w*(32*72);             // wave-private 4.6KB

  // ---- LN in registers -> A-frags ----
  short8 af[2][6];
  #pragma unroll
  for (int mr=0; mr<2; ++mr){
    const long r = (long)(m0 + w*32 + mr*16 + fr)*192;
    f32x4 v[6][2];
    float s = 0.f;
    #pragma unroll
    for (int ks=0; ks<6; ++ks){
      v[ks][0] = *(const f32x4*)(xio + r + ks*32 + g*8);
      v[ks][1] = *(const f32x4*)(xio + r + ks*32 + g*8 + 4);
      #pragma unroll
      for (int e=0;e<4;++e) s += v[ks][0][e] + v[ks][1][e];
    }
    s += __shfl_xor(s,16); s += __shfl_xor(s,32);
    const float mu = s*(1.0f/192.0f);
    float q = 0.f;
    #pragma unroll
    for (int ks=0; ks<6; ++ks)
      #pragma unroll
      for (int h=0;h<2;++h)
        #pragma unroll
        for (int e=0;e<4;++e){ const float d = v[ks][h][e]-mu; q += d*d; }
    q += __shfl_xor(q,16); q += __shfl_xor(q,32);
    const float rstd = rsqrtf(q*(1.0f/192.0f)+1e-5f);
    #pragma unroll
    for (int ks=0; ks<6; ++ks){
      const int c0 = ks*32 + g*8;
      #pragma unroll
      for (int h=0;h<2;++h)
        #pragma unroll
        for (int e=0;e<4;++e)
          af[mr][ks][h*4+e] =
            (short)f2b((v[ks][h][e]-mu)*rstd*lw[c0+h*4+e] + lb[c0+h*4+e]);
    }
  }

  f32x4 acc2[2][12];
  #pragma unroll
  for (int a=0;a<2;++a)
    #pragma unroll
    for (int n=0;n<12;++n) acc2[a][n] = (f32x4){0.f,0.f,0.f,0.f};

  for (int p=0; p<12; ++p){            // NO barriers inside
    // fc1: 32 rows x 64 h-cols, packed-burst B
    f32x4 a1[2][4];
    #pragma unroll
    for (int a=0;a<2;++a)
      #pragma unroll
      for (int n=0;n<4;++n) a1[a][n] = (f32x4){0.f,0.f,0.f,0.f};
    #pragma unroll
    for (int ks=0;ks<6;++ks){
      #pragma unroll
      for (int nr=0;nr<4;++nr){
        const short8 bf = *(const short8*)(w1 + ((((p*4+nr)*6+ks)<<6) + lane)*8);
        a1[0][nr] = __builtin_amdgcn_mfma_f32_16x16x32_bf16(af[0][ks], bf, a1[0][nr], 0,0,0);
        a1[1][nr] = __builtin_amdgcn_mfma_f32_16x16x32_bf16(af[1][ks], bf, a1[1][nr], 0,0,0);
      }
    }
    // rcp-gelu -> wave-private Hs (32 rows x 64 cols, stride 72)
    #pragma unroll
    for (int mr=0;mr<2;++mr)
      #pragma unroll
      for (int nr=0;nr<4;++nr){
        const float bc = b1[p*64 + nr*16 + fr];
        #pragma unroll
        for (int i=0;i<4;++i)
          hs[(mr*16+g*4+i)*72 + nr*16+fr] = f2b(gelu_f(a1[mr][nr][i] + bc));
      }
    // fc2 partial
    #pragma unroll
    for (int ks2=0;ks2<2;++ks2){
      const short8 ah0 = *(const short8*)&hs[(fr   )*72 + ks2*32 + g*8];
      const short8 ah1 = *(const short8*)&hs[(16+fr)*72 + ks2*32 + g*8];
      #pragma unroll
      for (int nr2=0;nr2<12;++nr2){
        const short8 bf = *(const short8*)(w2 + ((((p*12+nr2)*2+ks2)<<6) + lane)*8);
        acc2[0][nr2] = __builtin_amdgcn_mfma_f32_16x16x32_bf16(ah0, bf, acc2[0][nr2], 0,0,0);
        acc2[1][nr2] = __builtin_amdgcn_mfma_f32_16x16x32_bf16(ah1, bf, acc2[1][nr2], 0,0,0);
      }
    }
  }

  // ---- epilogue: out = xio + acc2 + b2; 64-token half-passes via LDS ----
  float* fbuf = (float*)SB;
  #pragma unroll
  for (int hp=0; hp<2; ++hp){
    #pragma unroll
    for (int ch=0;ch<2;++ch){
      __syncthreads();                 // retires Hs reads (first) / fbuf reads
      if ((w>>1) == hp){
        #pragma unroll
        for (int mr=0;mr<2;++mr)
          #pragma unroll
          for (int nr=0;nr<6;++nr){
            const float bc = b2[ch*96 + nr*16 + fr];
            #pragma unroll
            for (int i=0;i<4;++i)
              fbuf[((w&1)*32+mr*16+g*4+i)*100 + nr*16+fr] = acc2[mr][ch*6+nr][i] + bc;
          }
      }
      __syncthreads();
      #pragma unroll
      for (int j=0;j<6;++j){
        const int idx = tid + j*256, t = idx/24, cc = idx%24;
        const long o = (long)(m0 + hp*64 + t)*192 + ch*96 + cc*4;
        f32x4 v = *(const f32x4*)&fbuf[t*100 + cc*4];
        const f32x4 r = *(const f32x4*)(xio + o);
        #pragma unroll
        for (int e=0;e<4;++e) v[e] += r[e];
        *(f32x4*)(out + o) = v;
      }
    }
  }
}

// ------- conv3x3 implicit GEMM v4 (rcp-gelu) -------------------------------
template<int EPI, int CG, int IC, int OCT, int OCP, int NR, int TG>
__global__ __launch_bounds__(256, 2) void conv4_k(
    const u16* __restrict__ A, const u16* __restrict__ Wt,
    const float* __restrict__ bias, u16* __restrict__ outb,
    float* __restrict__ ssum)
{
  constexpr int NTG = 9/TG, S = CG*NTG;
  constexpr int WN = (TG*OCP*4 + 255)/256;
  __shared__ __align__(16) u16 Ah[4*130*36];
  __shared__ __align__(16) u16 Wl[TG*OCP*36];
  const int tid = threadIdx.x, w = tid>>6, lane = tid&63;
  const int fr = lane&15, g = lane>>4;
  const int b = blockIdx.x>>6, y0 = (blockIdx.x&63)*2;
  const int oc0 = blockIdx.y*OCP;
  const int wrow = w>>1, wcol = (w&1)*64;

  f32x4 acc[4][NR];
  #pragma unroll
  for (int a=0;a<4;++a)
    #pragma unroll
    for (int n=0;n<NR;++n) acc[a][n] = (f32x4){0.f,0.f,0.f,0.f};

  short8 hreg[8], wreg[WN];

  #define PRELOAD(s) { \
    const int cg_=(s)/NTG, tg_=(s)%NTG; \
    if (tg_==0){ \
      _Pragma("unroll") \
      for (int i=0;i<8;++i){ \
        const int id=tid+i*256, p=id>>9, x=(id>>2)&127, cc=id&3, y=y0+p-1; \
        short8 v={0,0,0,0,0,0,0,0}; \
        if ((unsigned)y<128u) \
          v = *(const short8*)(A + (long)((((b<<7)|y)<<7)|x)*IC + cg_*32 + cc*8); \
        hreg[i]=v; } } \
    _Pragma("unroll") \
    for (int i=0;i<WN;++i){ \
      const int id=tid+i*256; \
      if (id < TG*OCP*4){ \
        const int t=id/(OCP*4), r=id%(OCP*4), oc=r>>2, cc=r&3; \
        wreg[i] = *(const short8*)(Wt + \
            (long)((tg_*TG+t)*OCT + oc0 + oc)*IC + cg_*32 + cc*8); } } }

  #define STORE_STAGED(s) { \
    const int tg_=(s)%NTG; \
    if (tg_==0){ \
      _Pragma("unroll") \
      for (int i=0;i<8;++i){ \
        const int id=tid+i*256, p=id>>9, x=(id>>2)&127, cc=id&3; \
        *(short8*)&Ah[(p*130 + x + 1)*36 + cc*8] = hreg[i]; } \
      if (tid < 32){ \
        const int p=tid>>3, r=tid&7, col=(r>>2)?129:0, cc=r&3; \
        *(short8*)&Ah[(p*130 + col)*36 + cc*8] = (short8){0,0,0,0,0,0,0,0}; } } \
    _Pragma("unroll") \
    for (int i=0;i<WN;++i){ \
      const int id=tid+i*256; \
      if (id < TG*OCP*4){ \
        const int t=id/(OCP*4), r=id%(OCP*4), oc=r>>2, cc=r&3; \
        *(short8*)&Wl[(t*OCP+oc)*36 + cc*8] = wreg[i]; } } }

  #define COMPUTE(s) { \
    const int tg_=(s)%NTG; \
    _Pragma("unroll") \
    for (int t=0;t<TG;++t){ \
      const int tap=tg_*TG+t, dy=tap/3, dx=tap%3; \
      short8 bf[NR]; \
      _Pragma("unroll") \
      for (int nr=0;nr<NR;++nr) \
        bf[nr] = *(const short8*)&Wl[(t*OCP + nr*16 + fr)*36 + g*8]; \
      short8 af2[4]; \
      _Pragma("unroll") \
      for (int mr=0;mr<4;++mr) \
        af2[mr] = *(const short8*)&Ah[((wrow+dy)*130 + wcol + mr*16 + fr + dx)*36 + g*8]; \
      _Pragma("unroll") \
      for (int mr=0;mr<4;++mr) \
        _Pragma("unroll") \
        for (int nr=0;nr<NR;++nr) \
          acc[mr][nr] = __builtin_amdgcn_mfma_f32_16x16x32_bf16(af2[mr], bf[nr], acc[mr][nr], 0,0,0); } }

  PRELOAD(0);
  for (int s=0; s<S; ++s){
    __syncthreads();
    STORE_STAGED(s);
    __syncthreads();
    if (s+1 < S) PRELOAD(s+1);
    COMPUTE(s);
  }
  #undef PRELOAD
  #undef STORE_STAGED
  #undef COMPUTE

  if constexpr (EPI==2){
    #pragma unroll
    for (int nr=0;nr<NR;++nr){
      const float bc = bias[oc0 + nr*16 + fr];
      float s = 0.f;
      #pragma unroll
      for (int mr=0;mr<4;++mr)
        #pragma unroll
        for (int i=0;i<4;++i) s += acc[mr][nr][i] + bc;
      s += __shfl_xor(s,16); s += __shfl_xor(s,32);
      if (lane < 16) atomicAdd(&ssum[b*192 + oc0 + nr*16 + lane], s);
    }
  }

  u16* ob = Ah;
  const long tb = (long)(((b<<7)|y0)<<7);
  __syncthreads();
  if constexpr (EPI==1){
    #pragma unroll
    for (int mr=0;mr<4;++mr)
      #pragma unroll
      for (int nr=0;nr<NR;++nr){
        const float bc = bias[nr*16 + fr];
        #pragma unroll
        for (int i=0;i<4;++i){
          const int tok = wrow*128 + wcol + mr*16 + g*4 + i;
          ob[tok*72 + nr*16+fr] = f2b(gelu_f(acc[mr][nr][i] + bc));
        }
      }
    __syncthreads();
    #pragma unroll
    for (int j=0;j<8;++j){
      const int idx = tid + j*256, tok = idx>>3, cc = idx&7;
      *(short8*)(outb + (tb+tok)*OCP + cc*8) = *(const short8*)&ob[tok*72 + cc*8];
    }
  } else {
    const long pbase = (long)blockIdx.y*C2PLANE;
    #pragma unroll
    for (int h=0;h<2;++h){
      if (h) __syncthreads();
      if (wrow == h){
        #pragma unroll
        for (int mr=0;mr<4;++mr)
          #pragma unroll
          for (int nr=0;nr<NR;++nr){
            const float bc = bias[oc0 + nr*16 + fr];
            #pragma unroll
            for (int i=0;i<4;++i){
              const int tok = wcol + mr*16 + g*4 + i;
              ob[tok*104 + nr*16+fr] = f2b(acc[mr][nr][i] + bc);
            }
          }
      }
      __syncthreads();
      #pragma unroll
      for (int j=0;j<6;++j){
        const int idx = tid + j*256, t = idx/12, cc = idx%12;
        *(short8*)(outb + pbase + (tb + h*128 + t)*96 + cc*8) =
            *(const short8*)&ob[t*104 + cc*8];
      }
    }
  }
}

// ------------- SE MLP ------------------------------------------------------
__global__ __launch_bounds__(256) void se_k(const float* __restrict__ ssum,
    const float* __restrict__ ca1w, const float* __restrict__ ca1b,
    const float* __restrict__ ca2w, const float* __restrict__ ca2b,
    float* __restrict__ sgate)
{
  __shared__ float hid[48];
  const int tid = threadIdx.x;
  if (tid < 48){
    int b = tid/6, cs = tid%6;
    float a = ca1b[cs];
    for (int c=0;c<192;++c) a += ssum[b*192+c]*(1.f/16384.f)*ca1w[cs*192+c];
    hid[tid] = fmaxf(a, 0.f);
  }
  __syncthreads();
  for (int o = tid; o < 1536; o += 256){
    int b = o/192, c = o%192;
    float a = ca2b[c];
    #pragma unroll
    for (int cs=0;cs<6;++cs) a += hid[b*6+cs]*ca2w[c*6+cs];
    sgate[o] = 1.f/(1.f+expf(-a));
  }
}

// ---------- MFMA windowed attention: 1 wave = 1 (window, head) -------------
// All LDS is WAVE-PRIVATE (lidx_s[w], region_s[w], p_s[w]): no barriers
// needed — intra-wave LDS ordering is handled by lgkmcnt.
__global__ __launch_bounds__(256) void attn_k(const u16* __restrict__ qkv,
    const float* __restrict__ rpbL, const float* __restrict__ scale6,
    u16* __restrict__ aout)
{
  __shared__ int  lidx_s[4][64];
  __shared__ char region_s[4][64];
  __shared__ __align__(16) u16 p_s[4][64*72];
  const int tid = threadIdx.x, w = tid>>6, lane = tid&63;
  const int task = blockIdx.x*4 + w;
  const int win = task/6, h = task - win*6;
  const int b = win>>8, wn = win&255, wy = wn>>4, wx = wn&15;
  {
    int i = lane>>3, j = lane&7;
    int hs = wy*8+i, ws = wx*8+j;
    lidx_s[w][lane] = (b<<14) | (((hs+4)&127)<<7) | ((ws+4)&127);
    int hb = hs<120?0:(hs<124?1:2), wb = ws<120?0:(ws<124?1:2);
    region_s[w][lane] = (char)(hb*3+wb);
  }
  const int g = lane>>4, l15 = lane&15;
  const bool edge = (wy==15) || (wx==15);
  const float scl = scale6[h];
  const f32x4 zf = {0.f,0.f,0.f,0.f};

  short8 kf[4];
  #pragma unroll
  for (int mt=0; mt<4; ++mt){
    const long base = (long)lidx_s[w][mt*16+l15]*576 + 192 + h*32 + g*8;
    short8 r = *(const short8*)(qkv + base);
    float f[8]; float ss = 0.f;
    #pragma unroll
    for (int e=0;e<8;++e){ f[e] = b2f((u16)r[e]); ss += f[e]*f[e]; }
    ss += __shfl_xor(ss,16); ss += __shfl_xor(ss,32);
    const float inv = 1.0f/fmaxf(sqrtf(ss), 1e-12f);
    #pragma unroll
    for (int e=0;e<8;++e) kf[mt][e] = (short)f2b(f[e]*inv);
  }

  #pragma unroll
  for (int nt=0; nt<4; ++nt){
    short8 qf;
    {
      const long base = (long)lidx_s[w][nt*16+l15]*576 + h*32 + g*8;
      short8 r = *(const short8*)(qkv + base);
      float f[8]; float ss = 0.f;
      #pragma unroll
      for (int e=0;e<8;++e){ f[e] = b2f((u16)r[e]); ss += f[e]*f[e]; }
      ss += __shfl_xor(ss,16); ss += __shfl_xor(ss,32);
      const float inv = 1.0f/fmaxf(sqrtf(ss), 1e-12f);
      #pragma unroll
      for (int e=0;e<8;++e) qf[e] = (short)f2b(f[e]*inv);
    }
    f32x4 st[4];
    #pragma unroll
    for (int mt=0; mt<4; ++mt)
      st[mt] = __builtin_amdgcn_mfma_f32_16x16x32_bf16(kf[mt], qf, zf, 0, 0, 0);
    float lv[16];
    const float* rp = rpbL + ((h*4+nt)*4)*256 + lane*4;
    const int rq = edge ? region_s[w][nt*16+l15] : 0;
    #pragma unroll
    for (int mt=0; mt<4; ++mt){
      const f32x4 rb = *(const f32x4*)(rp + mt*256);
      #pragma unroll
      for (int i=0;i<4;++i){
        float v = st[mt][i]*scl + rb[i];
        if (edge && region_s[w][mt*16+g*4+i] != rq) v -= 100.0f;
        lv[mt*4+i] = v;
      }
    }
    float mx = lv[0];
    #pragma unroll
    for (int t=1;t<16;++t) mx = fmaxf(mx, lv[t]);
    mx = fmaxf(mx, __shfl_xor(mx,16)); mx = fmaxf(mx, __shfl_xor(mx,32));
    float sum = 0.f;
    #pragma unroll
    for (int t=0;t<16;++t){ lv[t] = __expf(lv[t]-mx); sum += lv[t]; }
    sum += __shfl_xor(sum,16); sum += __shfl_xor(sum,32);
    const float isum = 1.0f/sum;
    u16* pr = p_s[w] + (nt*16+l15)*72;
    #pragma unroll
    for (int mt=0; mt<4; ++mt){
      #pragma unroll
      for (int j=0;j<2;++j){
        unsigned lo = f2b(lv[mt*4+2*j]  *isum);
        unsigned hi = f2b(lv[mt*4+2*j+1]*isum);
        *(unsigned*)(pr + mt*16 + g*4 + 2*j) = lo | (hi<<16);
      }
    }
  }

  short8 vf[2][2];
  #pragma unroll
  for (int nd=0; nd<2; ++nd)
    #pragma unroll
    for (int kc=0; kc<2; ++kc)
      #pragma unroll
      for (int e=0;e<8;++e){
        const int tok = kc*32 + g*8 + e;
        vf[nd][kc][e] = (short)qkv[(long)lidx_s[w][tok]*576 + 384 + h*32 + nd*16 + l15];
      }

  #pragma unroll
  for (int mt=0; mt<4; ++mt){
    const short8 a0 = *(const short8*)(p_s[w] + (mt*16+l15)*72 +      g*8);
    const short8 a1 = *(const short8*)(p_s[w] + (mt*16+l15)*72 + 32 + g*8);
    #pragma unroll
    for (int nd=0; nd<2; ++nd){
      f32x4 o = __builtin_amdgcn_mfma_f32_16x16x32_bf16(a0, vf[nd][0], zf, 0, 0, 0);
      o = __builtin_amdgcn_mfma_f32_16x16x32_bf16(a1, vf[nd][1], o, 0, 0, 0);
      #pragma unroll
      for (int i=0;i<4;++i){
        const int q = mt*16 + g*4 + i;
        aout[(long)lidx_s[w][q]*192 + h*32 + nd*16 + l15] = f2b(o[i]);
      }
    }
  }
}

// ---------------------------------------------------------------------------
extern "C" void kernel_launch(void* const* d_in, const int* in_sizes, int n_in,
                              void* d_out, int out_size, void* d_ws, size_t ws_size,
                              hipStream_t stream)
{
  const float* x     = (const float*)d_in[0];
  const float* n1w   = (const float*)d_in[3];
  const float* n1b   = (const float*)d_in[4];
  const float* qkvw  = (const float*)d_in[5];
  const float* qb    = (const float*)d_in[6];
  const float* vb    = (const float*)d_in[7];
  const float* lgs   = (const float*)d_in[8];
  const float* cpb1w = (const float*)d_in[9];
  const float* cpb1b = (const float*)d_in[10];
  const float* cpb2w = (const float*)d_in[11];
  const float* projw = (const float*)d_in[12];
  const float* projb = (const float*)d_in[13];
  const float* cab1w = (const float*)d_in[14];
  const float* cab1b = (const float*)d_in[15];
  const float* cab2w = (const float*)d_in[16];
  const float* cab2b = (const float*)d_in[17];
  const float* ca1w  = (const float*)d_in[18];
  const float* ca1b  = (const float*)d_in[19];
  const float* ca2w  = (const float*)d_in[20];
  const float* ca2b  = (const float*)d_in[21];
  const float* n2w   = (const float*)d_in[22];
  const float* n2b   = (const float*)d_in[23];
  const float* fc1w  = (const float*)d_in[24];
  const float* fc1b  = (const float*)d_in[25];
  const float* fc2w  = (const float*)d_in[26];
  const float* fc2b  = (const float*)d_in[27];
  float* dout = (float*)d_out;
  char* ws = (char*)d_ws;

  constexpr size_t OFF_XN  = 0;
  constexpr size_t OFF_G1  = 50331648;
  constexpr size_t OFF_C2  = 67108864;
  constexpr size_t OFF_AO  = 167772160;
  constexpr size_t OFF_QKV = 218103808;
  constexpr size_t OFF_SM  = 369098752;

  u16*   xn      = (u16*)(ws + OFF_XN);
  u16*   g1      = (u16*)(ws + OFF_G1);
  u16*   c2      = (u16*)(ws + OFF_C2);
  u16*   ao      = (u16*)(ws + OFF_AO);
  u16*   qkvb    = (u16*)(ws + OFF_QKV);
  float* qkvbias = (float*)(ws + OFF_SM);
  float* scale6  = (float*)(ws + OFF_SM + 4096);
  float* ssum    = (float*)(ws + OFF_SM + 8192);
  float* sgate   = (float*)(ws + OFF_SM + 16384);
  float* rpbL    = (float*)(ws + OFF_SM + 24576);
  u16*   wqkv    = (u16*)(ws + OFF_SM + 131072);
  u16*   wproj   = (u16*)(ws + OFF_SM + 360448);
  u16*   wfc1    = (u16*)(ws + OFF_SM + 434176);
  u16*   wfc2    = (u16*)(ws + OFF_SM + 729088);
  u16*   wt1     = (u16*)(ws + OFF_SM + 1024000);
  u16*   wt2     = (u16*)(ws + OFF_SM + 1245184);

  prep_k<<<2595, 256, 0, stream>>>(qkvw, qb, vb, projw, fc1w, fc2w, cab1w, cab2w,
                                   lgs, qkvbias, wqkv, wproj, wfc1, wfc2, wt1, wt2, scale6);
  rpb_k<<<1, 256, 0, stream>>>(cpb1w, cpb1b, cpb2w, rpbL, ssum);
  ln_k<<<32768, 256, 0, stream>>>(x, n1w, n1b, xn);
  conv4_k<1,6,192,64,64,4,9><<<dim3(512,1), 256, 0, stream>>>(xn, wt1, cab1b, g1, nullptr);
  conv4_k<2,2,64,192,96,6,3><<<dim3(512,2), 256, 0, stream>>>(g1, wt2, cab2b, c2, ssum);
  se_k<<<1, 256, 0, stream>>>(ssum, ca1w, ca1b, ca2w, ca2b, sgate);
  gemm4_k<0,192,576><<<1024, 256, 0, stream>>>(xn, wqkv, qkvbias, qkvb);
  attn_k<<<3072, 256, 0, stream>>>(qkvb, rpbL, scale6, ao);
  proj_k<<<2048, 256, 0, stream>>>(ao, wproj, projb, x, c2, sgate, dout);
  mlp_k<<<1024, 256, 0, stream>>>(dout, n2w, n2b, wfc1, fc1b, wfc2, fc2b, dout);
}